// Round 1
// baseline (1684.194 us; speedup 1.0000x reference)
//
#include <hip/hip_runtime.h>

#define T_TOK 2048
#define S_LEN 1024
#define HIDN  2880
#define NHQ   64
#define NHKV  8
#define DH    64
#define QSZ   4096
#define KVSZ  512
#define WIN   128

typedef __attribute__((ext_vector_type(4))) float f32x4;
typedef __attribute__((ext_vector_type(8))) short bf16x8;
typedef __attribute__((ext_vector_type(4))) short bf16x4;

__device__ __forceinline__ unsigned short f2bf(float f) {
  unsigned u = __float_as_uint(f);
  u += 0x7fffu + ((u >> 16) & 1u);
  return (unsigned short)(u >> 16);
}
__device__ __forceinline__ float bf2f(short s) {
  return __uint_as_float(((unsigned)(unsigned short)s) << 16);
}

// ---------------- GEMM: C[M,N] = A[M,K] @ B[K,N] + bias ----------------
// 128x128 tile, BK=32, 4 waves in 2x2, each wave 4x4 mfma_f32_16x16x32_bf16.
// A staged [128][32] bf16 (row-major); B staged transposed [128][40] bf16
// (pad 40 keeps ds_read_b128 16B-aligned and banks uniform).
__global__ __launch_bounds__(256) void gemm_bias_kernel(
    const float* __restrict__ A, const float* __restrict__ Bw,
    const float* __restrict__ bias, float* __restrict__ C,
    int M, int N, int K)
{
  __shared__ short As[128][32];
  __shared__ short Bs[128][40];
  const int tid  = threadIdx.x;
  const int lane = tid & 63;
  const int wid  = tid >> 6;
  const int m0 = blockIdx.y * 128;
  const int n0 = blockIdx.x * 128;
  const int wm = (wid >> 1) * 64;
  const int wn = (wid & 1) * 64;

  f32x4 acc[4][4];
  #pragma unroll
  for (int i = 0; i < 4; ++i)
    #pragma unroll
    for (int j = 0; j < 4; ++j) acc[i][j] = (f32x4){0.f, 0.f, 0.f, 0.f};

  const int ar  = tid >> 3;          // A row group (0..31), +32 per iter
  const int ak  = (tid & 7) << 2;    // A k offset (0..28 step 4)
  const int bn  = tid & 127;         // B column within tile
  const int bk0 = (tid >> 7) << 2;   // 0 or 4
  const int gn  = n0 + bn;
  const bool bok = gn < N;

  const int fr = lane & 15;          // fragment row/col within 16-tile
  const int fk = (lane >> 4) << 3;   // fragment k offset (0..24 step 8)

  for (int k0 = 0; k0 < K; k0 += 32) {
    #pragma unroll
    for (int r = 0; r < 4; ++r) {
      const int row = ar + r * 32;
      const f32x4 av = *(const f32x4*)(A + (m0 + row) * K + k0 + ak);
      bf16x4 p;
      p[0] = (short)f2bf(av[0]); p[1] = (short)f2bf(av[1]);
      p[2] = (short)f2bf(av[2]); p[3] = (short)f2bf(av[3]);
      *(bf16x4*)&As[row][ak] = p;
    }
    #pragma unroll
    for (int r = 0; r < 4; ++r) {
      const int kk = bk0 + r * 8;    // covers {0,8,16,24} or {4,12,20,28}
      const float* bp = Bw + (k0 + kk) * N + gn;
      float x0 = 0.f, x1 = 0.f, x2 = 0.f, x3 = 0.f;
      if (bok) { x0 = bp[0]; x1 = bp[N]; x2 = bp[2 * N]; x3 = bp[3 * N]; }
      bf16x4 p;
      p[0] = (short)f2bf(x0); p[1] = (short)f2bf(x1);
      p[2] = (short)f2bf(x2); p[3] = (short)f2bf(x3);
      *(bf16x4*)&Bs[bn][kk] = p;
    }
    __syncthreads();

    bf16x8 af[4], bf[4];
    #pragma unroll
    for (int mt = 0; mt < 4; ++mt)
      af[mt] = *(const bf16x8*)&As[wm + mt * 16 + fr][fk];
    #pragma unroll
    for (int nt = 0; nt < 4; ++nt)
      bf[nt] = *(const bf16x8*)&Bs[wn + nt * 16 + fr][fk];
    #pragma unroll
    for (int mt = 0; mt < 4; ++mt)
      #pragma unroll
      for (int nt = 0; nt < 4; ++nt)
        acc[mt][nt] = __builtin_amdgcn_mfma_f32_16x16x32_bf16(
            af[mt], bf[nt], acc[mt][nt], 0, 0, 0);
    __syncthreads();
  }

  // C/D layout: col = lane&15, row = (lane>>4)*4 + reg (m89/m91-verified)
  const int r4 = (lane >> 4) << 2;
  const int cc = lane & 15;
  #pragma unroll
  for (int nt = 0; nt < 4; ++nt) {
    const int n = n0 + wn + nt * 16 + cc;
    if (n >= N) continue;
    const float bv = bias[n];
    #pragma unroll
    for (int mt = 0; mt < 4; ++mt) {
      const int mbase = m0 + wm + mt * 16 + r4;
      #pragma unroll
      for (int i = 0; i < 4; ++i)
        C[(mbase + i) * N + n] = acc[mt][nt][i] + bv;
    }
  }
}

// ---------------- RoPE (NeoX halves), in-place on q and k ----------------
__global__ __launch_bounds__(256) void rope_kernel(
    float* __restrict__ q, float* __restrict__ kb, const int* __restrict__ pos)
{
  const int idx = blockIdx.x * 256 + threadIdx.x;
  const int i  = idx & 31;
  const int th = idx >> 5;
  const int h  = th % 72;            // 64 q heads + 8 k heads
  const int t  = th / 72;
  if (t >= T_TOK) return;
  float* base = (h < 64) ? (q + t * QSZ + h * DH)
                         : (kb + t * KVSZ + (h - 64) * DH);
  const float x1 = base[i];
  const float x2 = base[i + 32];
  // inv_freq = THETA^(-i/32), log2(150000) = 17.1946023
  const float ang = (float)pos[t] * exp2f((float)i * (-17.1946023f / 32.0f));
  float sv, cv;
  sincosf(ang, &sv, &cv);
  base[i]      = x1 * cv - x2 * sv;
  base[i + 32] = x1 * sv + x2 * cv;
}

// ---------------- Sliding-window GQA attention ----------------
// block = (64-query chunk, kv head, batch); K/V window (192 rows) in bf16 LDS.
// QK: lane = key (3 passes of 64 for the 129-key window), q in fp32 registers.
// PV: lane = dim, p broadcast via v_readlane (scalar pipe).
__global__ __launch_bounds__(256) void attn_kernel(
    const float* __restrict__ q, const float* __restrict__ kbuf,
    const float* __restrict__ vbuf, float* __restrict__ obuf)
{
  __shared__ short Ks[192][72];
  __shared__ short Vs[192][72];
  const int tid  = threadIdx.x;
  const int lane = tid & 63;
  const int wid  = tid >> 6;
  const int sq0  = blockIdx.x * 64;
  const int kvh  = blockIdx.y;
  const int b    = blockIdx.z;
  const int kp0  = sq0 - WIN;

  for (int idx = tid; idx < 192 * 16; idx += 256) {
    const int w  = idx >> 4;
    const int d4 = (idx & 15) << 2;
    int kp = kp0 + w;
    if (kp < 0) kp = 0;                       // clamp; masked in softmax
    const int gbase = (b * S_LEN + kp) * KVSZ + kvh * DH + d4;
    const f32x4 kv = *(const f32x4*)(kbuf + gbase);
    const f32x4 vv = *(const f32x4*)(vbuf + gbase);
    bf16x4 pk, pv;
    pk[0] = (short)f2bf(kv[0]); pk[1] = (short)f2bf(kv[1]);
    pk[2] = (short)f2bf(kv[2]); pk[3] = (short)f2bf(kv[3]);
    pv[0] = (short)f2bf(vv[0]); pv[1] = (short)f2bf(vv[1]);
    pv[2] = (short)f2bf(vv[2]); pv[3] = (short)f2bf(vv[3]);
    *(bf16x4*)&Ks[w][d4] = pk;
    *(bf16x4*)&Vs[w][d4] = pv;
  }
  __syncthreads();

  for (int g = 0; g < 8; ++g) {
    const int h = kvh * 8 + g;
    for (int qi = wid; qi < 64; qi += 4) {
      const int s = sq0 + qi;
      const float* qp = q + (b * S_LEN + s) * QSZ + h * DH;
      float qreg[64];
      #pragma unroll
      for (int d = 0; d < 64; d += 4) {
        const f32x4 t4 = *(const f32x4*)(qp + d);
        qreg[d] = t4[0]; qreg[d + 1] = t4[1];
        qreg[d + 2] = t4[2]; qreg[d + 3] = t4[3];
      }
      float sc[3];
      #pragma unroll
      for (int kk = 0; kk < 3; ++kk) {
        const int jj = kk * 64 + lane;        // key offset within window
        const int wj = qi + jj;               // LDS window row
        float a = 0.f;
        if (jj <= 128) {
          #pragma unroll
          for (int d8 = 0; d8 < 64; d8 += 8) {
            const bf16x8 kv8 = *(const bf16x8*)&Ks[wj][d8];
            #pragma unroll
            for (int u = 0; u < 8; ++u)
              a = fmaf(bf2f(kv8[u]), qreg[d8 + u], a);
          }
        }
        const int kp = kp0 + wj;              // absolute key position
        sc[kk] = (jj <= 128 && kp >= 0) ? a * 0.125f : -1e30f;
      }
      float mx = fmaxf(sc[0], fmaxf(sc[1], sc[2]));
      #pragma unroll
      for (int off = 32; off > 0; off >>= 1)
        mx = fmaxf(mx, __shfl_xor(mx, off, 64));
      const float e0 = __expf(sc[0] - mx);
      const float e1 = __expf(sc[1] - mx);
      const float e2 = __expf(sc[2] - mx);
      float sm = e0 + e1 + e2;
      #pragma unroll
      for (int off = 32; off > 0; off >>= 1)
        sm += __shfl_xor(sm, off, 64);
      const float inv = 1.0f / sm;

      float oacc = 0.f;
      #pragma unroll 16
      for (int j = 0; j < 64; ++j) {
        const float p = __uint_as_float(
            __builtin_amdgcn_readlane(__float_as_uint(e0), j));
        oacc = fmaf(p, bf2f(Vs[qi + j][lane]), oacc);
      }
      #pragma unroll 16
      for (int j = 0; j < 64; ++j) {
        const float p = __uint_as_float(
            __builtin_amdgcn_readlane(__float_as_uint(e1), j));
        oacc = fmaf(p, bf2f(Vs[qi + 64 + j][lane]), oacc);
      }
      {
        const float p = __uint_as_float(
            __builtin_amdgcn_readlane(__float_as_uint(e2), 0));
        oacc = fmaf(p, bf2f(Vs[qi + 128][lane]), oacc);
      }
      obuf[(b * S_LEN + s) * QSZ + h * DH + lane] = oacc * inv;
    }
  }
}

extern "C" void kernel_launch(void* const* d_in, const int* in_sizes, int n_in,
                              void* d_out, int out_size, void* d_ws, size_t ws_size,
                              hipStream_t stream) {
  const float* hidden    = (const float*)d_in[0];
  const int*   positions = (const int*)d_in[1];
  const float* Wq = (const float*)d_in[2];
  const float* bq = (const float*)d_in[3];
  const float* Wk = (const float*)d_in[4];
  const float* bk = (const float*)d_in[5];
  const float* Wv = (const float*)d_in[6];
  const float* bv = (const float*)d_in[7];
  const float* Wo = (const float*)d_in[8];
  const float* bo = (const float*)d_in[9];
  float* out = (float*)d_out;

  // workspace layout (fp32): q[2048*4096] k[2048*512] v[2048*512] o[2048*4096]
  float* qb = (float*)d_ws;
  float* kb = qb + (size_t)T_TOK * QSZ;
  float* vb = kb + (size_t)T_TOK * KVSZ;
  float* ob = vb + (size_t)T_TOK * KVSZ;

  const dim3 blk(256);
  gemm_bias_kernel<<<dim3(QSZ / 128, T_TOK / 128), blk, 0, stream>>>(
      hidden, Wq, bq, qb, T_TOK, QSZ, HIDN);
  gemm_bias_kernel<<<dim3(KVSZ / 128, T_TOK / 128), blk, 0, stream>>>(
      hidden, Wk, bk, kb, T_TOK, KVSZ, HIDN);
  gemm_bias_kernel<<<dim3(KVSZ / 128, T_TOK / 128), blk, 0, stream>>>(
      hidden, Wv, bv, vb, T_TOK, KVSZ, HIDN);
  rope_kernel<<<dim3((T_TOK * 72 * 32) / 256), blk, 0, stream>>>(
      qb, kb, positions);
  attn_kernel<<<dim3(S_LEN / 64, NHKV, 2), blk, 0, stream>>>(qb, kb, vb, ob);
  gemm_bias_kernel<<<dim3((HIDN + 127) / 128, T_TOK / 128), blk, 0, stream>>>(
      ob, Wo, bo, out, T_TOK, HIDN, QSZ);
}

// Round 2
// 545.340 us; speedup vs baseline: 3.0883x; 3.0883x over previous
//
#include <hip/hip_runtime.h>

#define T_TOK 2048
#define S_LEN 1024
#define HIDN  2880
#define NHQ   64
#define NHKV  8
#define DH    64
#define QSZ   4096
#define KVSZ  512
#define WIN   128

typedef __attribute__((ext_vector_type(4))) float f32x4;
typedef __attribute__((ext_vector_type(8))) short bf16x8;

__device__ __forceinline__ unsigned short f2bf(float f) {
  unsigned u = __float_as_uint(f);
  u += 0x7fffu + ((u >> 16) & 1u);
  return (unsigned short)(u >> 16);
}
__device__ __forceinline__ float bf2f(unsigned short s) {
  return __uint_as_float(((unsigned)s) << 16);
}

// async 16B global->LDS (m97 pattern). LDS dest must be wave-uniform base
// + lane*16; caller guarantees contiguity.
__device__ __forceinline__ void ld_g2l16(const void* g, void* l) {
  __builtin_amdgcn_global_load_lds(
      (const __attribute__((address_space(1))) unsigned int*)g,
      (__attribute__((address_space(3))) unsigned int*)l, 16, 0, 0);
}

// ---------------- hidden fp32 -> bf16 ----------------
__global__ __launch_bounds__(256) void convert_hidden(
    const float* __restrict__ in, unsigned short* __restrict__ out)
{
  const size_t off = ((size_t)blockIdx.x * 256 + threadIdx.x) * 8;
  const f32x4 a = *(const f32x4*)(in + off);
  const f32x4 b = *(const f32x4*)(in + off + 4);
  bf16x8 p;
  p[0] = (short)f2bf(a[0]); p[1] = (short)f2bf(a[1]);
  p[2] = (short)f2bf(a[2]); p[3] = (short)f2bf(a[3]);
  p[4] = (short)f2bf(b[0]); p[5] = (short)f2bf(b[1]);
  p[6] = (short)f2bf(b[2]); p[7] = (short)f2bf(b[3]);
  *(bf16x8*)(out + off) = p;
}

// ---------------- W [K][N] fp32 -> WT [Npad][K] bf16 (zero pad) -----------
__global__ __launch_bounds__(256) void transpose_w(
    const float* __restrict__ W, unsigned short* __restrict__ WT,
    int K, int N, int Npad)
{
  __shared__ float tile[32][33];
  const int c  = threadIdx.x & 31;
  const int r0 = threadIdx.x >> 5;          // 0..7
  const int nb = blockIdx.x * 32;
  const int kb = blockIdx.y * 32;
  #pragma unroll
  for (int rr = 0; rr < 4; ++rr) {
    const int kk = r0 + rr * 8;
    const int gn = nb + c;
    tile[kk][c] = (gn < N) ? W[(size_t)(kb + kk) * N + gn] : 0.f;
  }
  __syncthreads();
  #pragma unroll
  for (int rr = 0; rr < 4; ++rr) {
    const int nn = r0 + rr * 8;
    WT[(size_t)(nb + nn) * K + kb + c] = f2bf(tile[c][nn]);
  }
}

// ---------------- GEMM: C = A[M,K] @ BT[N,K]^T + bias (m97 structure) -----
// MODE 0: bf16 C[M][N] (N%128==0); MODE 1: f32 C[M][N], n<N guard;
// MODE 2: bf16 C^T[N][M] (N%128==0)
template <int MODE>
__global__ __launch_bounds__(256) void gemm_bt(
    const unsigned short* __restrict__ A, const unsigned short* __restrict__ BT,
    const float* __restrict__ bias, void* __restrict__ Cv,
    int M, int N, int K)
{
  __shared__ unsigned short As[128 * 32];
  __shared__ unsigned short Bs[128 * 32];
  const int tid  = threadIdx.x;
  const int lane = tid & 63;
  const int wid  = tid >> 6;
  const int m0 = blockIdx.y * 128;
  const int n0 = blockIdx.x * 128;
  const int wm = (wid >> 1) * 64;
  const int wn = (wid & 1) * 64;
  const int fr = lane & 15;
  const int fk = (lane >> 4) * 8;

  f32x4 acc[4][4];
  #pragma unroll
  for (int i = 0; i < 4; ++i)
    #pragma unroll
    for (int j = 0; j < 4; ++j) acc[i][j] = (f32x4){0.f, 0.f, 0.f, 0.f};

  const int arow = tid >> 2;            // 0..63 (chunk row), +64 for 2nd chunk
  const int akc  = (tid & 3) * 8;       // k element offset of 16B chunk
  const unsigned short* Ap = A + (size_t)(m0 + arow) * K + akc;
  const unsigned short* Bp = BT + (size_t)(n0 + arow) * K + akc;
  const size_t rowstep = (size_t)64 * K;

  for (int k0 = 0; k0 < K; k0 += 32) {
    ld_g2l16(Ap + k0,           &As[tid * 8]);
    ld_g2l16(Ap + rowstep + k0, &As[2048 + tid * 8]);
    ld_g2l16(Bp + k0,           &Bs[tid * 8]);
    ld_g2l16(Bp + rowstep + k0, &Bs[2048 + tid * 8]);
    __syncthreads();
    bf16x8 af[4], bfr[4];
    #pragma unroll
    for (int mt = 0; mt < 4; ++mt)
      af[mt] = *(const bf16x8*)&As[(wm + mt * 16 + fr) * 32 + fk];
    #pragma unroll
    for (int nt = 0; nt < 4; ++nt)
      bfr[nt] = *(const bf16x8*)&Bs[(wn + nt * 16 + fr) * 32 + fk];
    #pragma unroll
    for (int mt = 0; mt < 4; ++mt)
      #pragma unroll
      for (int nt = 0; nt < 4; ++nt)
        acc[mt][nt] = __builtin_amdgcn_mfma_f32_16x16x32_bf16(
            af[mt], bfr[nt], acc[mt][nt], 0, 0, 0);
    __syncthreads();
  }

  // C/D layout: col = lane&15, row = (lane>>4)*4 + reg
  const int r4 = (lane >> 4) * 4;
  #pragma unroll
  for (int nt = 0; nt < 4; ++nt) {
    const int n = n0 + wn + nt * 16 + fr;
    if (MODE == 1 && n >= N) continue;
    const float bv = bias[n];
    #pragma unroll
    for (int mt = 0; mt < 4; ++mt) {
      const int mb = m0 + wm + mt * 16 + r4;
      #pragma unroll
      for (int i = 0; i < 4; ++i) {
        const float v = acc[mt][nt][i] + bv;
        if (MODE == 0)
          ((unsigned short*)Cv)[(size_t)(mb + i) * N + n] = f2bf(v);
        else if (MODE == 1)
          ((float*)Cv)[(size_t)(mb + i) * N + n] = v;
        else
          ((unsigned short*)Cv)[(size_t)n * M + (mb + i)] = f2bf(v);
      }
    }
  }
}

// ---------------- RoPE (NeoX), in place on bf16 q and k ----------------
__global__ __launch_bounds__(256) void rope_kernel(
    unsigned short* __restrict__ q, unsigned short* __restrict__ kb,
    const int* __restrict__ pos)
{
  const int idx = blockIdx.x * 256 + threadIdx.x;
  const int i  = idx & 31;
  const int th = idx >> 5;
  const int h  = th % 72;
  const int t  = th / 72;
  if (t >= T_TOK) return;
  unsigned short* base = (h < 64) ? (q + (size_t)t * QSZ + h * DH)
                                  : (kb + (size_t)t * KVSZ + (h - 64) * DH);
  const float x1 = bf2f(base[i]);
  const float x2 = bf2f(base[i + 32]);
  // inv_freq = THETA^(-i/32); log2(150000) = 17.19460283
  const float ang = (float)pos[t] * exp2f((float)i * (-17.19460283f / 32.0f));
  float sv, cv;
  sincosf(ang, &sv, &cv);
  base[i]      = f2bf(x1 * cv - x2 * sv);
  base[i + 32] = f2bf(x1 * sv + x2 * cv);
}

// ---------------- MFMA sliding-window GQA attention ----------------
// block = (64-query chunk, head, batch). 4 waves; wave w owns 16 queries.
// Phase 1: QK^T (K natural layout). Phase 2: softmax in regs.
// Phase 3: P -> LDS (A-layout), V^T staged over K's LDS. Phase 4: PV.
__global__ __launch_bounds__(256) void attn_kernel(
    const unsigned short* __restrict__ q, const unsigned short* __restrict__ k,
    const unsigned short* __restrict__ vT, unsigned short* __restrict__ o)
{
  __shared__ unsigned short Qs[64 * 72];    //  9216 B
  __shared__ unsigned short KVs[192 * 72];  // 27648 B: K[192][72], then Vt[64][200]
  __shared__ unsigned short Ps[64 * 200];   // 25600 B
  const int tid  = threadIdx.x;
  const int lane = tid & 63;
  const int wid  = tid >> 6;
  const int sq0  = blockIdx.x * 64;
  const int h    = blockIdx.y;
  const int b    = blockIdx.z;
  const int kvh  = h >> 3;
  const int kp0  = sq0 - WIN;

  // stage Q (64x64) and K window (192x64)
  #pragma unroll
  for (int j = 0; j < 2; ++j) {
    const int c  = tid + j * 256;
    const int qr = c >> 3, dc = (c & 7) * 8;
    const bf16x8 vv = *(const bf16x8*)(
        q + (size_t)(b * S_LEN + sq0 + qr) * QSZ + h * DH + dc);
    *(bf16x8*)&Qs[qr * 72 + dc] = vv;
  }
  #pragma unroll
  for (int j = 0; j < 6; ++j) {
    const int c  = tid + j * 256;
    const int kr = c >> 3, dc = (c & 7) * 8;
    int tok = b * S_LEN + kp0 + kr;
    if (tok < 0) tok = 0;                   // masked later
    const bf16x8 vv = *(const bf16x8*)(k + (size_t)tok * KVSZ + kvh * DH + dc);
    *(bf16x8*)&KVs[kr * 72 + dc] = vv;
  }
  __syncthreads();

  const int fr = lane & 15;
  const int fk = (lane >> 4) * 8;
  const int qw = wid * 16;

  // QK^T: S[q 16][key 192]
  f32x4 S[12];
  #pragma unroll
  for (int i = 0; i < 12; ++i) S[i] = (f32x4){0.f, 0.f, 0.f, 0.f};
  #pragma unroll
  for (int ks = 0; ks < 2; ++ks) {
    const bf16x8 af = *(const bf16x8*)&Qs[(qw + fr) * 72 + ks * 32 + fk];
    #pragma unroll
    for (int nt = 0; nt < 12; ++nt) {
      const bf16x8 bfr = *(const bf16x8*)&KVs[(nt * 16 + fr) * 72 + ks * 32 + fk];
      S[nt] = __builtin_amdgcn_mfma_f32_16x16x32_bf16(af, bfr, S[nt], 0, 0, 0);
    }
  }

  // mask + scale + softmax. Row r of C lives in lanes lane>>4 == r>>2, reg r&3.
  const int qbase = sq0 + qw + ((lane >> 4) << 2);   // + i = absolute query
  float mrow[4] = {-3e38f, -3e38f, -3e38f, -3e38f};
  #pragma unroll
  for (int nt = 0; nt < 12; ++nt) {
    const int jpos = kp0 + nt * 16 + fr;             // absolute key position
    #pragma unroll
    for (int i = 0; i < 4; ++i) {
      const int qa = qbase + i;
      const bool valid = (jpos >= 0) && (jpos <= qa) && (jpos >= qa - WIN);
      const float sc = valid ? S[nt][i] * 0.125f : -1e30f;
      S[nt][i] = sc;
      mrow[i] = fmaxf(mrow[i], sc);
    }
  }
  #pragma unroll
  for (int off = 1; off < 16; off <<= 1)
    #pragma unroll
    for (int i = 0; i < 4; ++i)
      mrow[i] = fmaxf(mrow[i], __shfl_xor(mrow[i], off, 64));
  float lsum[4] = {0.f, 0.f, 0.f, 0.f};
  #pragma unroll
  for (int nt = 0; nt < 12; ++nt)
    #pragma unroll
    for (int i = 0; i < 4; ++i) {
      const float e = __expf(S[nt][i] - mrow[i]);    // masked -> 0
      S[nt][i] = e;
      lsum[i] += e;
    }
  #pragma unroll
  for (int off = 1; off < 16; off <<= 1)
    #pragma unroll
    for (int i = 0; i < 4; ++i)
      lsum[i] += __shfl_xor(lsum[i], off, 64);
  float inv[4];
  #pragma unroll
  for (int i = 0; i < 4; ++i) inv[i] = 1.0f / lsum[i];

  __syncthreads();   // all waves done reading KVs (K)

  // write unnormalized P (C-layout -> row-major [q][key])
  #pragma unroll
  for (int nt = 0; nt < 12; ++nt)
    #pragma unroll
    for (int i = 0; i < 4; ++i)
      Ps[(qbase - sq0 + i) * 200 + nt * 16 + fr] = f2bf(S[nt][i]);

  // stage V^T [64 dims][192 keys] over KVs
  if (kp0 >= 0) {
    #pragma unroll
    for (int j = 0; j < 6; ++j) {
      const int c  = tid + j * 256;
      const int dr = c / 24, kc = (c % 24) * 8;
      const bf16x8 vv = *(const bf16x8*)(
          vT + (size_t)(kvh * DH + dr) * T_TOK + b * S_LEN + kp0 + kc);
      *(bf16x8*)&KVs[dr * 200 + kc] = vv;
    }
  } else {
    #pragma unroll
    for (int j = 0; j < 6; ++j) {
      const int c  = tid + j * 256;
      const int dr = c / 24, kc = (c % 24) * 8;
      bf16x8 vv;
      #pragma unroll
      for (int u = 0; u < 8; ++u) {
        int col = b * S_LEN + kp0 + kc + u;
        if (col < 0) col = 0;                        // p==0 there
        vv[u] = (short)vT[(size_t)(kvh * DH + dr) * T_TOK + col];
      }
      *(bf16x8*)&KVs[dr * 200 + kc] = vv;
    }
  }
  __syncthreads();

  // PV: O[16 q][64 d] = P[16][192] @ V[192][64]
  f32x4 O[4];
  #pragma unroll
  for (int i = 0; i < 4; ++i) O[i] = (f32x4){0.f, 0.f, 0.f, 0.f};
  #pragma unroll
  for (int ks = 0; ks < 6; ++ks) {
    const bf16x8 pa = *(const bf16x8*)&Ps[(qw + fr) * 200 + ks * 32 + fk];
    #pragma unroll
    for (int nt = 0; nt < 4; ++nt) {
      const bf16x8 vb = *(const bf16x8*)&KVs[(nt * 16 + fr) * 200 + ks * 32 + fk];
      O[nt] = __builtin_amdgcn_mfma_f32_16x16x32_bf16(pa, vb, O[nt], 0, 0, 0);
    }
  }
  #pragma unroll
  for (int nt = 0; nt < 4; ++nt)
    #pragma unroll
    for (int i = 0; i < 4; ++i)
      o[(size_t)(b * S_LEN + qbase + i) * QSZ + h * DH + nt * 16 + fr] =
          f2bf(O[nt][i] * inv[i]);
}

extern "C" void kernel_launch(void* const* d_in, const int* in_sizes, int n_in,
                              void* d_out, int out_size, void* d_ws, size_t ws_size,
                              hipStream_t stream) {
  const float* hidden    = (const float*)d_in[0];
  const int*   positions = (const int*)d_in[1];
  const float* Wq = (const float*)d_in[2];
  const float* bq = (const float*)d_in[3];
  const float* Wk = (const float*)d_in[4];
  const float* bk = (const float*)d_in[5];
  const float* Wv = (const float*)d_in[6];
  const float* bv = (const float*)d_in[7];
  const float* Wo = (const float*)d_in[8];
  const float* bo = (const float*)d_in[9];
  float* out = (float*)d_out;

  // workspace layout (bytes), total 62,783,488:
  //   hbf  [2048][2880] bf16            @ 0
  //   R1: WqT [4096][2880] bf16, later WoT [2944][4096] bf16
  //   WkT  [512][2880] bf16
  //   WvT  [512][2880] bf16
  //   q/o  [2048][4096] bf16   (attention writes o in place of q)
  //   k    [2048][512]  bf16
  //   vT   [512][2048]  bf16
  char* ws = (char*)d_ws;
  unsigned short* hbf = (unsigned short*)(ws);
  unsigned short* R1  = (unsigned short*)(ws + 11796480);
  unsigned short* WkT = (unsigned short*)(ws + 35913728);
  unsigned short* WvT = (unsigned short*)(ws + 38862848);
  unsigned short* qb  = (unsigned short*)(ws + 41811968);
  unsigned short* kb  = (unsigned short*)(ws + 58589184);
  unsigned short* vTb = (unsigned short*)(ws + 60686336);

  const dim3 blk(256);
  convert_hidden<<<dim3((T_TOK * HIDN) / (256 * 8)), blk, 0, stream>>>(hidden, hbf);
  transpose_w<<<dim3(QSZ / 32, HIDN / 32), blk, 0, stream>>>(Wq, R1, HIDN, QSZ, QSZ);
  transpose_w<<<dim3(KVSZ / 32, HIDN / 32), blk, 0, stream>>>(Wk, WkT, HIDN, KVSZ, KVSZ);
  transpose_w<<<dim3(KVSZ / 32, HIDN / 32), blk, 0, stream>>>(Wv, WvT, HIDN, KVSZ, KVSZ);

  gemm_bt<0><<<dim3(QSZ / 128, T_TOK / 128), blk, 0, stream>>>(
      hbf, R1, bq, qb, T_TOK, QSZ, HIDN);
  gemm_bt<0><<<dim3(KVSZ / 128, T_TOK / 128), blk, 0, stream>>>(
      hbf, WkT, bk, kb, T_TOK, KVSZ, HIDN);
  gemm_bt<2><<<dim3(KVSZ / 128, T_TOK / 128), blk, 0, stream>>>(
      hbf, WvT, bv, vTb, T_TOK, KVSZ, HIDN);

  // WoT (2944 rows, zero-padded) overwrites R1 after Q-GEMM consumed WqT
  transpose_w<<<dim3(2944 / 32, QSZ / 32), blk, 0, stream>>>(Wo, R1, QSZ, HIDN, 2944);

  rope_kernel<<<dim3((T_TOK * 72 * 32) / 256), blk, 0, stream>>>(qb, kb, positions);
  attn_kernel<<<dim3(S_LEN / 64, NHQ, 2), blk, 0, stream>>>(qb, kb, vTb, qb);
  gemm_bt<1><<<dim3((HIDN + 127) / 128, T_TOK / 128), blk, 0, stream>>>(
      qb, R1, bo, out, T_TOK, HIDN, QSZ);
}

// Round 3
// 400.191 us; speedup vs baseline: 4.2085x; 1.3627x over previous
//
#include <hip/hip_runtime.h>

#define T_TOK 2048
#define S_LEN 1024
#define HIDN  2880
#define NHQ   64
#define NHKV  8
#define DH    64
#define QSZ   4096
#define KVSZ  512
#define WIN   128
#define NQKV  5120
#define NOPAD 2944

typedef __attribute__((ext_vector_type(4))) float f32x4;
typedef __attribute__((ext_vector_type(8))) short bf16x8;
typedef __attribute__((ext_vector_type(4))) short s16x4;

__device__ __forceinline__ unsigned short f2bf(float f) {
  unsigned u = __float_as_uint(f);
  u += 0x7fffu + ((u >> 16) & 1u);
  return (unsigned short)(u >> 16);
}
__device__ __forceinline__ float bf2f(unsigned short s) {
  return __uint_as_float(((unsigned)s) << 16);
}
__device__ __forceinline__ void ld_g2l16(const void* g, void* l) {
  __builtin_amdgcn_global_load_lds(
      (const __attribute__((address_space(1))) unsigned int*)g,
      (__attribute__((address_space(3))) unsigned int*)l, 16, 0, 0);
}

// ---------------- hidden fp32 -> bf16 ----------------
__global__ __launch_bounds__(256) void convert_hidden(
    const float* __restrict__ in, unsigned short* __restrict__ out)
{
  const size_t off = ((size_t)blockIdx.x * 256 + threadIdx.x) * 8;
  const f32x4 a = *(const f32x4*)(in + off);
  const f32x4 b = *(const f32x4*)(in + off + 4);
  bf16x8 p;
  p[0] = (short)f2bf(a[0]); p[1] = (short)f2bf(a[1]);
  p[2] = (short)f2bf(a[2]); p[3] = (short)f2bf(a[3]);
  p[4] = (short)f2bf(b[0]); p[5] = (short)f2bf(b[1]);
  p[6] = (short)f2bf(b[2]); p[7] = (short)f2bf(b[3]);
  *(bf16x8*)(out + off) = p;
}

// ---- W [K][N] fp32 -> WT [Npad][K] bf16, zero-pad; tile 32k x 64n --------
// grid = (Npad/64, K/32). short4 stores: 8 lanes cover 64 contiguous bytes.
__global__ __launch_bounds__(256) void transpose_w(
    const float* __restrict__ W, unsigned short* __restrict__ WT,
    int K, int N)
{
  __shared__ float tile[32][65];
  const int tid = threadIdx.x;
  const int nb = blockIdx.x * 64;
  const int kb = blockIdx.y * 32;
  {
    const int n2 = (tid & 31) * 2;
    const int k0 = tid >> 5;
    #pragma unroll
    for (int r = 0; r < 4; ++r) {
      const int k = k0 + r * 8;
      const int gn = nb + n2;
      const size_t base = (size_t)(kb + k) * N;
      tile[k][n2]     = (gn     < N) ? W[base + gn]     : 0.f;
      tile[k][n2 + 1] = (gn + 1 < N) ? W[base + gn + 1] : 0.f;
    }
  }
  __syncthreads();
  {
    const int k4 = (tid & 7) * 4;
    const int n0 = tid >> 3;
    #pragma unroll
    for (int r = 0; r < 2; ++r) {
      const int n = n0 + r * 32;
      s16x4 p;
      p[0] = (short)f2bf(tile[k4][n]);     p[1] = (short)f2bf(tile[k4 + 1][n]);
      p[2] = (short)f2bf(tile[k4 + 2][n]); p[3] = (short)f2bf(tile[k4 + 3][n]);
      *(s16x4*)(WT + (size_t)(nb + n) * K + kb + k4) = p;
    }
  }
}

// ---------------- GEMM core: 128x128 tile, BK=64, xor-swizzled LDS --------
// LDS chunk layout: chunk c of row r lives at r*64 + ((c^(r&7))*8) elements.
// Staging via global_load_lds picks the matching global chunk so the wave's
// LDS dests stay base+lane*16 contiguous; fragment b128 reads land 2-way
// (free) on banks instead of 8-way.
__device__ __forceinline__ void gemm_core(
    const unsigned short* __restrict__ A, const unsigned short* __restrict__ BT,
    int K, int m0, int n0, unsigned short* As, unsigned short* Bs,
    f32x4 acc[4][4])
{
  const int tid  = threadIdx.x;
  const int lane = tid & 63;
  const int wid  = tid >> 6;
  const int wm = (wid >> 1) * 64;
  const int wn = (wid & 1) * 64;
  const int fr = lane & 15;
  const int fq = lane >> 4;              // 0..3

  const int rsub = tid >> 3;             // 0..31
  const int cg   = (tid & 7) ^ (rsub & 7);
  const unsigned short* Ap = A  + (size_t)(m0 + rsub) * K + cg * 8;
  const unsigned short* Bp = BT + (size_t)(n0 + rsub) * K + cg * 8;
  const size_t rstep = (size_t)32 * K;

  for (int k0 = 0; k0 < K; k0 += 64) {
    #pragma unroll
    for (int i = 0; i < 4; ++i) {
      ld_g2l16(Ap + i * rstep + k0, As + ((size_t)i * 256 + tid) * 8);
      ld_g2l16(Bp + i * rstep + k0, Bs + ((size_t)i * 256 + tid) * 8);
    }
    __syncthreads();
    #pragma unroll
    for (int ks = 0; ks < 2; ++ks) {
      const int kc = ks * 4 + fq;        // global k-chunk 0..7
      bf16x8 af[4], bfr[4];
      #pragma unroll
      for (int mt = 0; mt < 4; ++mt) {
        const int R = wm + mt * 16 + fr;
        af[mt] = *(const bf16x8*)(As + R * 64 + ((kc ^ (R & 7)) << 3));
      }
      #pragma unroll
      for (int nt = 0; nt < 4; ++nt) {
        const int R = wn + nt * 16 + fr;
        bfr[nt] = *(const bf16x8*)(Bs + R * 64 + ((kc ^ (R & 7)) << 3));
      }
      #pragma unroll
      for (int mt = 0; mt < 4; ++mt)
        #pragma unroll
        for (int nt = 0; nt < 4; ++nt)
          acc[mt][nt] = __builtin_amdgcn_mfma_f32_16x16x32_bf16(
              af[mt], bfr[nt], acc[mt][nt], 0, 0, 0);
    }
    __syncthreads();
  }
}

// rope+bias epilogue for a 64-col group (one head per wave-column range).
// C/D layout col=lane&15, row=(lane>>4)*4+i; pairs (nt, nt+2) are (d, d+32).
__device__ __forceinline__ void rope_epilogue(
    f32x4 acc[4][4], const float* __restrict__ bias,
    const int* __restrict__ pos, unsigned short* __restrict__ outp,
    int outStride, int colbase, int rowbase, int lane)
{
  const int fr = lane & 15;
  const int r4 = (lane >> 4) * 4;
  const float invf0 = exp2f((float)fr        * (-17.19460283f / 32.0f));
  const float invf1 = exp2f((float)(fr + 16) * (-17.19460283f / 32.0f));
  #pragma unroll
  for (int mt = 0; mt < 4; ++mt) {
    #pragma unroll
    for (int i = 0; i < 4; ++i) {
      const int m = rowbase + mt * 16 + r4 + i;
      const float p = (float)pos[m];
      #pragma unroll
      for (int ntp = 0; ntp < 2; ++ntp) {
        float sv, cv;
        __sincosf(p * (ntp ? invf1 : invf0), &sv, &cv);
        const int c1 = colbase + ntp * 16 + fr;
        const float x1 = acc[mt][ntp][i]     + bias[c1];
        const float x2 = acc[mt][ntp + 2][i] + bias[c1 + 32];
        outp[(size_t)m * outStride + c1]      = f2bf(x1 * cv - x2 * sv);
        outp[(size_t)m * outStride + c1 + 32] = f2bf(x1 * sv + x2 * cv);
      }
    }
  }
}

// ---------------- fused QKV GEMM (+rope for Q/K, transposed V) ------------
__global__ __launch_bounds__(256) void gemm_qkv(
    const unsigned short* __restrict__ A, const unsigned short* __restrict__ BT,
    const float* __restrict__ bq, const float* __restrict__ bk,
    const float* __restrict__ bv, const int* __restrict__ pos,
    unsigned short* __restrict__ qb, unsigned short* __restrict__ kb,
    unsigned short* __restrict__ vT)
{
  __shared__ unsigned short As[128 * 64];
  __shared__ unsigned short Bs[128 * 64];
  const int m0 = blockIdx.y * 128;
  const int n0 = blockIdx.x * 128;
  f32x4 acc[4][4];
  #pragma unroll
  for (int i = 0; i < 4; ++i)
    #pragma unroll
    for (int j = 0; j < 4; ++j) acc[i][j] = (f32x4){0.f, 0.f, 0.f, 0.f};
  gemm_core(A, BT, HIDN, m0, n0, As, Bs, acc);

  const int lane = threadIdx.x & 63;
  const int wid  = threadIdx.x >> 6;
  const int wm = (wid >> 1) * 64;
  const int wn = (wid & 1) * 64;
  const int fr = lane & 15;
  const int r4 = (lane >> 4) * 4;

  if (n0 < QSZ) {
    rope_epilogue(acc, bq, pos, qb, QSZ, n0 + wn, m0 + wm, lane);
  } else if (n0 < QSZ + KVSZ) {
    rope_epilogue(acc, bk, pos, kb, KVSZ, n0 - QSZ + wn, m0 + wm, lane);
  } else {
    #pragma unroll
    for (int nt = 0; nt < 4; ++nt) {
      const int vrow = n0 - (QSZ + KVSZ) + wn + nt * 16 + fr;
      const float bvv = bv[vrow];
      #pragma unroll
      for (int mt = 0; mt < 4; ++mt) {
        const int mb = m0 + wm + mt * 16 + r4;
        s16x4 p;
        p[0] = (short)f2bf(acc[mt][nt][0] + bvv);
        p[1] = (short)f2bf(acc[mt][nt][1] + bvv);
        p[2] = (short)f2bf(acc[mt][nt][2] + bvv);
        p[3] = (short)f2bf(acc[mt][nt][3] + bvv);
        *(s16x4*)(vT + (size_t)vrow * T_TOK + mb) = p;
      }
    }
  }
}

// ---------------- O-projection GEMM (fp32 out, N=2880 guard) --------------
__global__ __launch_bounds__(256) void gemm_o(
    const unsigned short* __restrict__ A, const unsigned short* __restrict__ BT,
    const float* __restrict__ bias, float* __restrict__ C)
{
  __shared__ unsigned short As[128 * 64];
  __shared__ unsigned short Bs[128 * 64];
  const int m0 = blockIdx.y * 128;
  const int n0 = blockIdx.x * 128;
  f32x4 acc[4][4];
  #pragma unroll
  for (int i = 0; i < 4; ++i)
    #pragma unroll
    for (int j = 0; j < 4; ++j) acc[i][j] = (f32x4){0.f, 0.f, 0.f, 0.f};
  gemm_core(A, BT, QSZ, m0, n0, As, Bs, acc);

  const int lane = threadIdx.x & 63;
  const int wid  = threadIdx.x >> 6;
  const int wm = (wid >> 1) * 64;
  const int wn = (wid & 1) * 64;
  const int fr = lane & 15;
  const int r4 = (lane >> 4) * 4;
  #pragma unroll
  for (int nt = 0; nt < 4; ++nt) {
    const int n = n0 + wn + nt * 16 + fr;
    if (n >= HIDN) continue;
    const float bvv = bias[n];
    #pragma unroll
    for (int mt = 0; mt < 4; ++mt) {
      const int mb = m0 + wm + mt * 16 + r4;
      #pragma unroll
      for (int i = 0; i < 4; ++i)
        C[(size_t)(mb + i) * HIDN + n] = acc[mt][nt][i] + bvv;
    }
  }
}

// ---------------- MFMA sliding-window GQA attention ----------------
// LDS union (52 KB -> 3 blocks/CU): K[192][72] aliased later by Vt[64][200];
// Q[64][72] aliased later by P[64][200]. No softmax max-pass (scores <= ~18).
__global__ __launch_bounds__(256) void attn_kernel(
    const unsigned short* __restrict__ q, const unsigned short* __restrict__ k,
    const unsigned short* __restrict__ vT, unsigned short* __restrict__ o)
{
  __shared__ unsigned short lds[26624];     // 53,248 B
  unsigned short* Ks = lds;                 // [192][72]
  unsigned short* Qs = lds + 13824;         // [64][72]
  unsigned short* Ps = lds + 13824;         // [64][200] (over Qs)
  unsigned short* Vt = lds;                 // [64][200] (over Ks)

  const int tid  = threadIdx.x;
  const int lane = tid & 63;
  const int wid  = tid >> 6;
  const int sq0  = blockIdx.x * 64;
  const int h    = blockIdx.y;
  const int b    = blockIdx.z;
  const int kvh  = h >> 3;
  const int kp0  = sq0 - WIN;

  #pragma unroll
  for (int j = 0; j < 2; ++j) {
    const int c  = tid + j * 256;
    const int qr = c >> 3, dc = (c & 7) * 8;
    const bf16x8 vv = *(const bf16x8*)(
        q + (size_t)(b * S_LEN + sq0 + qr) * QSZ + h * DH + dc);
    *(bf16x8*)&Qs[qr * 72 + dc] = vv;
  }
  #pragma unroll
  for (int j = 0; j < 6; ++j) {
    const int c  = tid + j * 256;
    const int kr = c >> 3, dc = (c & 7) * 8;
    int tok = b * S_LEN + kp0 + kr;
    if (tok < 0) tok = 0;                   // masked later
    const bf16x8 vv = *(const bf16x8*)(k + (size_t)tok * KVSZ + kvh * DH + dc);
    *(bf16x8*)&Ks[kr * 72 + dc] = vv;
  }
  __syncthreads();

  const int fr = lane & 15;
  const int fk = (lane >> 4) * 8;
  const int qw = wid * 16;

  f32x4 S[12];
  #pragma unroll
  for (int i = 0; i < 12; ++i) S[i] = (f32x4){0.f, 0.f, 0.f, 0.f};
  #pragma unroll
  for (int ks = 0; ks < 2; ++ks) {
    const bf16x8 af = *(const bf16x8*)&Qs[(qw + fr) * 72 + ks * 32 + fk];
    #pragma unroll
    for (int nt = 0; nt < 12; ++nt) {
      const bf16x8 bfr = *(const bf16x8*)&Ks[(nt * 16 + fr) * 72 + ks * 32 + fk];
      S[nt] = __builtin_amdgcn_mfma_f32_16x16x32_bf16(af, bfr, S[nt], 0, 0, 0);
    }
  }

  // mask + scale + exp (no max-pass; |score| <= ~18, fp32-safe)
  const int qbase = sq0 + qw + ((lane >> 4) << 2);
  float lsum[4] = {0.f, 0.f, 0.f, 0.f};
  #pragma unroll
  for (int nt = 0; nt < 12; ++nt) {
    const int jpos = kp0 + nt * 16 + fr;
    #pragma unroll
    for (int i = 0; i < 4; ++i) {
      const int qa = qbase + i;
      const bool valid = (jpos >= 0) && (jpos <= qa) && (jpos >= qa - WIN);
      const float e = valid ? __expf(S[nt][i] * 0.125f) : 0.f;
      S[nt][i] = e;
      lsum[i] += e;
    }
  }
  #pragma unroll
  for (int off = 1; off < 16; off <<= 1)
    #pragma unroll
    for (int i = 0; i < 4; ++i)
      lsum[i] += __shfl_xor(lsum[i], off, 64);
  float inv[4];
  #pragma unroll
  for (int i = 0; i < 4; ++i) inv[i] = 1.0f / lsum[i];

  __syncthreads();   // all waves done reading Qs/Ks

  #pragma unroll
  for (int nt = 0; nt < 12; ++nt)
    #pragma unroll
    for (int i = 0; i < 4; ++i)
      Ps[(qbase - sq0 + i) * 200 + nt * 16 + fr] = f2bf(S[nt][i]);

  if (kp0 >= 0) {
    #pragma unroll
    for (int j = 0; j < 6; ++j) {
      const int c  = tid + j * 256;
      const int dr = c / 24, kc = (c % 24) * 8;
      const bf16x8 vv = *(const bf16x8*)(
          vT + (size_t)(kvh * DH + dr) * T_TOK + b * S_LEN + kp0 + kc);
      *(bf16x8*)&Vt[dr * 200 + kc] = vv;
    }
  } else {
    #pragma unroll
    for (int j = 0; j < 6; ++j) {
      const int c  = tid + j * 256;
      const int dr = c / 24, kc = (c % 24) * 8;
      bf16x8 vv;
      #pragma unroll
      for (int u = 0; u < 8; ++u) {
        int col = b * S_LEN + kp0 + kc + u;
        if (col < 0) col = 0;               // p==0 there
        vv[u] = (short)vT[(size_t)(kvh * DH + dr) * T_TOK + col];
      }
      *(bf16x8*)&Vt[dr * 200 + kc] = vv;
    }
  }
  __syncthreads();

  f32x4 O[4];
  #pragma unroll
  for (int i = 0; i < 4; ++i) O[i] = (f32x4){0.f, 0.f, 0.f, 0.f};
  #pragma unroll
  for (int ks = 0; ks < 6; ++ks) {
    const bf16x8 pa = *(const bf16x8*)&Ps[(qw + fr) * 200 + ks * 32 + fk];
    #pragma unroll
    for (int nt = 0; nt < 4; ++nt) {
      const bf16x8 vb = *(const bf16x8*)&Vt[(nt * 16 + fr) * 200 + ks * 32 + fk];
      O[nt] = __builtin_amdgcn_mfma_f32_16x16x32_bf16(pa, vb, O[nt], 0, 0, 0);
    }
  }
  #pragma unroll
  for (int nt = 0; nt < 4; ++nt)
    #pragma unroll
    for (int i = 0; i < 4; ++i)
      o[(size_t)(b * S_LEN + qbase + i) * QSZ + h * DH + nt * 16 + fr] =
          f2bf(O[nt][i] * inv[i]);
}

extern "C" void kernel_launch(void* const* d_in, const int* in_sizes, int n_in,
                              void* d_out, int out_size, void* d_ws, size_t ws_size,
                              hipStream_t stream) {
  const float* hidden    = (const float*)d_in[0];
  const int*   positions = (const int*)d_in[1];
  const float* Wq = (const float*)d_in[2];
  const float* bq = (const float*)d_in[3];
  const float* Wk = (const float*)d_in[4];
  const float* bk = (const float*)d_in[5];
  const float* Wv = (const float*)d_in[6];
  const float* bv = (const float*)d_in[7];
  const float* Wo = (const float*)d_in[8];
  const float* bo = (const float*)d_in[9];
  float* out = (float*)d_out;

  // workspace (62,259,200 B total):
  //   hbf   [2048][2880] bf16        @ 0          (11,796,480)
  //   WqkvT [5120][2880] bf16        @ 11796480   (29,491,200) -- later WoT [2944][4096]
  //   q/o   [2048][4096] bf16        @ 41287680   (16,777,216)
  //   k     [2048][512]  bf16        @ 58064896   ( 2,097,152)
  //   vT    [512][2048]  bf16        @ 60162048   ( 2,097,152)
  char* ws = (char*)d_ws;
  unsigned short* hbf   = (unsigned short*)(ws);
  unsigned short* WqkvT = (unsigned short*)(ws + 11796480);
  unsigned short* qb    = (unsigned short*)(ws + 41287680);
  unsigned short* kb    = (unsigned short*)(ws + 58064896);
  unsigned short* vTb   = (unsigned short*)(ws + 60162048);

  const dim3 blk(256);
  convert_hidden<<<dim3((T_TOK * HIDN) / 2048), blk, 0, stream>>>(hidden, hbf);
  transpose_w<<<dim3(QSZ / 64, HIDN / 32), blk, 0, stream>>>(
      Wq, WqkvT, HIDN, QSZ);
  transpose_w<<<dim3(KVSZ / 64, HIDN / 32), blk, 0, stream>>>(
      Wk, WqkvT + (size_t)QSZ * HIDN, HIDN, KVSZ);
  transpose_w<<<dim3(KVSZ / 64, HIDN / 32), blk, 0, stream>>>(
      Wv, WqkvT + (size_t)(QSZ + KVSZ) * HIDN, HIDN, KVSZ);

  gemm_qkv<<<dim3(NQKV / 128, T_TOK / 128), blk, 0, stream>>>(
      hbf, WqkvT, bq, bk, bv, positions, qb, kb, vTb);

  // WoT (2944 padded rows) overwrites WqkvT after QKV GEMM consumed it
  transpose_w<<<dim3(NOPAD / 64, QSZ / 32), blk, 0, stream>>>(
      Wo, WqkvT, QSZ, HIDN);

  attn_kernel<<<dim3(S_LEN / 64, NHQ, 2), blk, 0, stream>>>(qb, kb, vTb, qb);
  gemm_o<<<dim3(NOPAD / 128, T_TOK / 128), blk, 0, stream>>>(
      qb, WqkvT, bo, out);
}

// Round 4
// 396.463 us; speedup vs baseline: 4.2480x; 1.0094x over previous
//
#include <hip/hip_runtime.h>

#define T_TOK 2048
#define S_LEN 1024
#define HIDN  2880
#define NHQ   64
#define NHKV  8
#define DH    64
#define QSZ   4096
#define KVSZ  512
#define WIN   128
#define NQKV  5120
#define NOPAD 2944

typedef __attribute__((ext_vector_type(4))) float f32x4;
typedef __attribute__((ext_vector_type(8))) short bf16x8;
typedef __attribute__((ext_vector_type(4))) short s16x4;

__device__ __forceinline__ unsigned short f2bf(float f) {
  unsigned u = __float_as_uint(f);
  u += 0x7fffu + ((u >> 16) & 1u);
  return (unsigned short)(u >> 16);
}
__device__ __forceinline__ float bf2f(unsigned short s) {
  return __uint_as_float(((unsigned)s) << 16);
}
__device__ __forceinline__ void ld_g2l16(const void* g, void* l) {
  __builtin_amdgcn_global_load_lds(
      (const __attribute__((address_space(1))) unsigned int*)g,
      (__attribute__((address_space(3))) unsigned int*)l, 16, 0, 0);
}

// ---------------- hidden fp32 -> bf16 ----------------
__global__ __launch_bounds__(256) void convert_hidden(
    const float* __restrict__ in, unsigned short* __restrict__ out)
{
  const size_t off = ((size_t)blockIdx.x * 256 + threadIdx.x) * 8;
  const f32x4 a = *(const f32x4*)(in + off);
  const f32x4 b = *(const f32x4*)(in + off + 4);
  bf16x8 p;
  p[0] = (short)f2bf(a[0]); p[1] = (short)f2bf(a[1]);
  p[2] = (short)f2bf(a[2]); p[3] = (short)f2bf(a[3]);
  p[4] = (short)f2bf(b[0]); p[5] = (short)f2bf(b[1]);
  p[6] = (short)f2bf(b[2]); p[7] = (short)f2bf(b[3]);
  *(bf16x8*)(out + off) = p;
}

// ---- W [K][N] fp32 -> WT [n][K] bf16; tile 32k x 64n; zero-pad n>=N ------
// Load: float4 x2/thread into tile[32][72] (stride 72: b128-aligned, 2-way
// free banks). Store: bf16x8/thread, read banks (8j+n)%32 -> 2-way free.
__global__ __launch_bounds__(256) void transpose_w(
    const float* __restrict__ W, unsigned short* __restrict__ WT,
    int K, int N)
{
  __shared__ float tile[32][72];
  const int tid = threadIdx.x;
  const int nb = blockIdx.x * 64;
  const int kb = blockIdx.y * 32;
  const int kk = tid >> 3;
  const int n8 = (tid & 7) * 8;
  if (nb + 64 <= N) {
    const float* src = W + (size_t)(kb + kk) * N + nb + n8;
    *(f32x4*)&tile[kk][n8]     = *(const f32x4*)(src);
    *(f32x4*)&tile[kk][n8 + 4] = *(const f32x4*)(src + 4);
  } else {
    #pragma unroll
    for (int u = 0; u < 8; ++u)
      tile[kk][n8 + u] = (nb + n8 + u < N)
          ? W[(size_t)(kb + kk) * N + nb + n8 + u] : 0.f;
  }
  __syncthreads();
  const int n  = tid & 63;
  const int k8 = (tid >> 6) * 8;
  bf16x8 p;
  #pragma unroll
  for (int j = 0; j < 8; ++j) p[j] = (short)f2bf(tile[k8 + j][n]);
  *(bf16x8*)(WT + (size_t)(nb + n) * K + kb + k8) = p;
}

// ---------------- GEMM core: 128x128 tile, BK=64, xor-swizzled LDS --------
__device__ __forceinline__ void gemm_core(
    const unsigned short* __restrict__ A, const unsigned short* __restrict__ BT,
    int K, int m0, int n0, unsigned short* As, unsigned short* Bs,
    f32x4 acc[4][4])
{
  const int tid  = threadIdx.x;
  const int lane = tid & 63;
  const int wid  = tid >> 6;
  const int wm = (wid >> 1) * 64;
  const int wn = (wid & 1) * 64;
  const int fr = lane & 15;
  const int fq = lane >> 4;

  const int rsub = tid >> 3;             // 0..31
  const int cg   = (tid & 7) ^ (rsub & 7);
  const unsigned short* Ap = A  + (size_t)(m0 + rsub) * K + cg * 8;
  const unsigned short* Bp = BT + (size_t)(n0 + rsub) * K + cg * 8;
  const size_t rstep = (size_t)32 * K;

  for (int k0 = 0; k0 < K; k0 += 64) {
    #pragma unroll
    for (int i = 0; i < 4; ++i) {
      ld_g2l16(Ap + i * rstep + k0, As + ((size_t)i * 256 + tid) * 8);
      ld_g2l16(Bp + i * rstep + k0, Bs + ((size_t)i * 256 + tid) * 8);
    }
    __syncthreads();
    #pragma unroll
    for (int ks = 0; ks < 2; ++ks) {
      const int kc = ks * 4 + fq;
      bf16x8 af[4], bfr[4];
      #pragma unroll
      for (int mt = 0; mt < 4; ++mt) {
        const int R = wm + mt * 16 + fr;
        af[mt] = *(const bf16x8*)(As + R * 64 + ((kc ^ (R & 7)) << 3));
      }
      #pragma unroll
      for (int nt = 0; nt < 4; ++nt) {
        const int R = wn + nt * 16 + fr;
        bfr[nt] = *(const bf16x8*)(Bs + R * 64 + ((kc ^ (R & 7)) << 3));
      }
      #pragma unroll
      for (int mt = 0; mt < 4; ++mt)
        #pragma unroll
        for (int nt = 0; nt < 4; ++nt)
          acc[mt][nt] = __builtin_amdgcn_mfma_f32_16x16x32_bf16(
              af[mt], bfr[nt], acc[mt][nt], 0, 0, 0);
    }
    __syncthreads();
  }
}

// rope+bias epilogue for a 64-col group. C/D: col=lane&15, row=(lane>>4)*4+i.
__device__ __forceinline__ void rope_epilogue(
    f32x4 acc[4][4], const float* __restrict__ bias,
    const int* __restrict__ pos, unsigned short* __restrict__ outp,
    int outStride, int colbase, int rowbase, int lane)
{
  const int fr = lane & 15;
  const int r4 = (lane >> 4) * 4;
  const float invf0 = exp2f((float)fr        * (-17.19460283f / 32.0f));
  const float invf1 = exp2f((float)(fr + 16) * (-17.19460283f / 32.0f));
  #pragma unroll
  for (int mt = 0; mt < 4; ++mt) {
    #pragma unroll
    for (int i = 0; i < 4; ++i) {
      const int m = rowbase + mt * 16 + r4 + i;
      const float p = (float)pos[m];
      #pragma unroll
      for (int ntp = 0; ntp < 2; ++ntp) {
        float sv, cv;
        __sincosf(p * (ntp ? invf1 : invf0), &sv, &cv);
        const int c1 = colbase + ntp * 16 + fr;
        const float x1 = acc[mt][ntp][i]     + bias[c1];
        const float x2 = acc[mt][ntp + 2][i] + bias[c1 + 32];
        outp[(size_t)m * outStride + c1]      = f2bf(x1 * cv - x2 * sv);
        outp[(size_t)m * outStride + c1 + 32] = f2bf(x1 * sv + x2 * cv);
      }
    }
  }
}

// ---------------- fused QKV GEMM (+rope for Q/K, transposed V) ------------
__global__ __launch_bounds__(256) void gemm_qkv(
    const unsigned short* __restrict__ A, const unsigned short* __restrict__ BT,
    const float* __restrict__ bq, const float* __restrict__ bk,
    const float* __restrict__ bv, const int* __restrict__ pos,
    unsigned short* __restrict__ qb, unsigned short* __restrict__ kb,
    unsigned short* __restrict__ vT)
{
  __shared__ unsigned short As[128 * 64];
  __shared__ unsigned short Bs[128 * 64];
  const int m0 = blockIdx.y * 128;
  const int n0 = blockIdx.x * 128;
  f32x4 acc[4][4];
  #pragma unroll
  for (int i = 0; i < 4; ++i)
    #pragma unroll
    for (int j = 0; j < 4; ++j) acc[i][j] = (f32x4){0.f, 0.f, 0.f, 0.f};
  gemm_core(A, BT, HIDN, m0, n0, As, Bs, acc);

  const int lane = threadIdx.x & 63;
  const int wid  = threadIdx.x >> 6;
  const int wm = (wid >> 1) * 64;
  const int wn = (wid & 1) * 64;
  const int fr = lane & 15;
  const int r4 = (lane >> 4) * 4;

  if (n0 < QSZ) {
    rope_epilogue(acc, bq, pos, qb, QSZ, n0 + wn, m0 + wm, lane);
  } else if (n0 < QSZ + KVSZ) {
    rope_epilogue(acc, bk, pos, kb, KVSZ, n0 - QSZ + wn, m0 + wm, lane);
  } else {
    #pragma unroll
    for (int nt = 0; nt < 4; ++nt) {
      const int vrow = n0 - (QSZ + KVSZ) + wn + nt * 16 + fr;
      const float bvv = bv[vrow];
      #pragma unroll
      for (int mt = 0; mt < 4; ++mt) {
        const int mb = m0 + wm + mt * 16 + r4;
        s16x4 p;
        p[0] = (short)f2bf(acc[mt][nt][0] + bvv);
        p[1] = (short)f2bf(acc[mt][nt][1] + bvv);
        p[2] = (short)f2bf(acc[mt][nt][2] + bvv);
        p[3] = (short)f2bf(acc[mt][nt][3] + bvv);
        *(s16x4*)(vT + (size_t)vrow * T_TOK + mb) = p;
      }
    }
  }
}

// ------- O-projection GEMM: 64m x 128n tile, 2 waves, BK=64, fp32 out -----
__global__ __launch_bounds__(128) void gemm_o(
    const unsigned short* __restrict__ A, const unsigned short* __restrict__ BT,
    const float* __restrict__ bias, float* __restrict__ C)
{
  __shared__ unsigned short As[64 * 64];
  __shared__ unsigned short Bs[128 * 64];
  const int tid  = threadIdx.x;
  const int lane = tid & 63;
  const int wid  = tid >> 6;             // 0..1
  const int m0 = blockIdx.y * 64;
  const int n0 = blockIdx.x * 128;
  const int wn = wid * 64;
  const int fr = lane & 15;
  const int fq = lane >> 4;

  f32x4 acc[4][4];
  #pragma unroll
  for (int i = 0; i < 4; ++i)
    #pragma unroll
    for (int j = 0; j < 4; ++j) acc[i][j] = (f32x4){0.f, 0.f, 0.f, 0.f};

  const int rsub = tid >> 3;             // 0..15
  const int cg   = (tid & 7) ^ (rsub & 7);
  const unsigned short* Ap = A  + (size_t)(m0 + rsub) * QSZ + cg * 8;
  const unsigned short* Bp = BT + (size_t)(n0 + rsub) * QSZ + cg * 8;
  const size_t rstep = (size_t)16 * QSZ;

  for (int k0 = 0; k0 < QSZ; k0 += 64) {
    #pragma unroll
    for (int i = 0; i < 4; ++i)
      ld_g2l16(Ap + i * rstep + k0, As + ((size_t)i * 128 + tid) * 8);
    #pragma unroll
    for (int i = 0; i < 8; ++i)
      ld_g2l16(Bp + i * rstep + k0, Bs + ((size_t)i * 128 + tid) * 8);
    __syncthreads();
    #pragma unroll
    for (int ks = 0; ks < 2; ++ks) {
      const int kc = ks * 4 + fq;
      bf16x8 af[4], bfr[4];
      #pragma unroll
      for (int mt = 0; mt < 4; ++mt) {
        const int R = mt * 16 + fr;
        af[mt] = *(const bf16x8*)(As + R * 64 + ((kc ^ (R & 7)) << 3));
      }
      #pragma unroll
      for (int nt = 0; nt < 4; ++nt) {
        const int R = wn + nt * 16 + fr;
        bfr[nt] = *(const bf16x8*)(Bs + R * 64 + ((kc ^ (R & 7)) << 3));
      }
      #pragma unroll
      for (int mt = 0; mt < 4; ++mt)
        #pragma unroll
        for (int nt = 0; nt < 4; ++nt)
          acc[mt][nt] = __builtin_amdgcn_mfma_f32_16x16x32_bf16(
              af[mt], bfr[nt], acc[mt][nt], 0, 0, 0);
    }
    __syncthreads();
  }

  const int r4 = (lane >> 4) * 4;
  #pragma unroll
  for (int nt = 0; nt < 4; ++nt) {
    const int n = n0 + wn + nt * 16 + fr;
    if (n >= HIDN) continue;
    const float bvv = bias[n];
    #pragma unroll
    for (int mt = 0; mt < 4; ++mt) {
      const int mb = m0 + mt * 16 + r4;
      #pragma unroll
      for (int i = 0; i < 4; ++i)
        C[(size_t)(mb + i) * HIDN + n] = acc[mt][nt][i] + bvv;
    }
  }
}

// ---------------- MFMA sliding-window GQA attention, 2 heads/block --------
// Grid (16 chunks, 32 head-pairs, 2). K window staged once per pair; Q read
// straight into A-fragments from global (no LDS); V^T aliases K after both
// heads' QK; P region shared serially between heads.
__global__ __launch_bounds__(256, 3) void attn_kernel(
    const unsigned short* __restrict__ q, const unsigned short* __restrict__ k,
    const unsigned short* __restrict__ vT, unsigned short* __restrict__ o)
{
  __shared__ unsigned short lds[26624];     // 53,248 B -> 3 blocks/CU
  unsigned short* Ks = lds;                 // [192][72]
  unsigned short* Vt = lds;                 // [64][200] (over Ks)
  unsigned short* Ps = lds + 13824;         // [64][200]

  const int tid  = threadIdx.x;
  const int lane = tid & 63;
  const int wid  = tid >> 6;
  const int sq0  = blockIdx.x * 64;
  const int hp   = blockIdx.y;
  const int b    = blockIdx.z;
  const int h0   = hp * 2;
  const int kvh  = hp >> 2;
  const int kp0  = sq0 - WIN;

  const int fr = lane & 15;
  const int fk = (lane >> 4) * 8;
  const int qw = wid * 16;

  // preload Q A-fragments for both heads (wave-private rows, global reads)
  bf16x8 qf[2][2];
  {
    const size_t qrow = (size_t)(b * S_LEN + sq0 + qw + fr) * QSZ;
    #pragma unroll
    for (int hh = 0; hh < 2; ++hh)
      #pragma unroll
      for (int ks2 = 0; ks2 < 2; ++ks2)
        qf[hh][ks2] = *(const bf16x8*)(q + qrow + (h0 + hh) * DH + ks2 * 32 + fk);
  }

  // stage K window (192 x 64)
  #pragma unroll
  for (int j = 0; j < 6; ++j) {
    const int c  = tid + j * 256;
    const int kr = c >> 3, dc = (c & 7) * 8;
    int tok = b * S_LEN + kp0 + kr;
    if (tok < 0) tok = 0;                   // masked later
    const bf16x8 vv = *(const bf16x8*)(k + (size_t)tok * KVSZ + kvh * DH + dc);
    *(bf16x8*)&Ks[kr * 72 + dc] = vv;
  }
  __syncthreads();

  // QK^T for both heads
  f32x4 S0[12], S1[12];
  #pragma unroll
  for (int i = 0; i < 12; ++i) {
    S0[i] = (f32x4){0.f, 0.f, 0.f, 0.f};
    S1[i] = (f32x4){0.f, 0.f, 0.f, 0.f};
  }
  #pragma unroll
  for (int ks2 = 0; ks2 < 2; ++ks2) {
    #pragma unroll
    for (int nt = 0; nt < 12; ++nt) {
      const bf16x8 bfr = *(const bf16x8*)&Ks[(nt * 16 + fr) * 72 + ks2 * 32 + fk];
      S0[nt] = __builtin_amdgcn_mfma_f32_16x16x32_bf16(qf[0][ks2], bfr, S0[nt], 0, 0, 0);
      S1[nt] = __builtin_amdgcn_mfma_f32_16x16x32_bf16(qf[1][ks2], bfr, S1[nt], 0, 0, 0);
    }
  }

  // mask + scale + exp (no max-pass; scores bounded), rowsum, both heads
  const int qbase = sq0 + qw + ((lane >> 4) << 2);
  float ls0[4] = {0.f, 0.f, 0.f, 0.f};
  float ls1[4] = {0.f, 0.f, 0.f, 0.f};
  #pragma unroll
  for (int nt = 0; nt < 12; ++nt) {
    const int jpos = kp0 + nt * 16 + fr;
    #pragma unroll
    for (int i = 0; i < 4; ++i) {
      const int qa = qbase + i;
      const bool valid = (jpos >= 0) && (jpos <= qa) && (jpos >= qa - WIN);
      const float e0 = valid ? __expf(S0[nt][i] * 0.125f) : 0.f;
      const float e1 = valid ? __expf(S1[nt][i] * 0.125f) : 0.f;
      S0[nt][i] = e0; ls0[i] += e0;
      S1[nt][i] = e1; ls1[i] += e1;
    }
  }
  #pragma unroll
  for (int off = 1; off < 16; off <<= 1)
    #pragma unroll
    for (int i = 0; i < 4; ++i) {
      ls0[i] += __shfl_xor(ls0[i], off, 64);
      ls1[i] += __shfl_xor(ls1[i], off, 64);
    }
  float inv0[4], inv1[4];
  #pragma unroll
  for (int i = 0; i < 4; ++i) {
    inv0[i] = 1.0f / ls0[i];
    inv1[i] = 1.0f / ls1[i];
  }
  __syncthreads();   // all waves done reading Ks

  // P0 -> LDS; stage V^T [64 d][192 keys] over Ks
  #pragma unroll
  for (int nt = 0; nt < 12; ++nt)
    #pragma unroll
    for (int i = 0; i < 4; ++i)
      Ps[(qbase - sq0 + i) * 200 + nt * 16 + fr] = f2bf(S0[nt][i]);
  if (kp0 >= 0) {
    #pragma unroll
    for (int j = 0; j < 6; ++j) {
      const int c  = tid + j * 256;
      const int dr = c / 24, kc = (c % 24) * 8;
      const bf16x8 vv = *(const bf16x8*)(
          vT + (size_t)(kvh * DH + dr) * T_TOK + b * S_LEN + kp0 + kc);
      *(bf16x8*)&Vt[dr * 200 + kc] = vv;
    }
  } else {
    #pragma unroll
    for (int j = 0; j < 6; ++j) {
      const int c  = tid + j * 256;
      const int dr = c / 24, kc = (c % 24) * 8;
      bf16x8 vv;
      #pragma unroll
      for (int u = 0; u < 8; ++u) {
        int col = b * S_LEN + kp0 + kc + u;
        if (col < 0) col = 0;               // p==0 there
        vv[u] = (short)vT[(size_t)(kvh * DH + dr) * T_TOK + col];
      }
      *(bf16x8*)&Vt[dr * 200 + kc] = vv;
    }
  }
  __syncthreads();

  // PV head 0
  {
    f32x4 O[4];
    #pragma unroll
    for (int i = 0; i < 4; ++i) O[i] = (f32x4){0.f, 0.f, 0.f, 0.f};
    #pragma unroll
    for (int ks2 = 0; ks2 < 6; ++ks2) {
      const bf16x8 pa = *(const bf16x8*)&Ps[(qw + fr) * 200 + ks2 * 32 + fk];
      #pragma unroll
      for (int nt = 0; nt < 4; ++nt) {
        const bf16x8 vb = *(const bf16x8*)&Vt[(nt * 16 + fr) * 200 + ks2 * 32 + fk];
        O[nt] = __builtin_amdgcn_mfma_f32_16x16x32_bf16(pa, vb, O[nt], 0, 0, 0);
      }
    }
    #pragma unroll
    for (int nt = 0; nt < 4; ++nt)
      #pragma unroll
      for (int i = 0; i < 4; ++i)
        o[(size_t)(b * S_LEN + qbase + i) * QSZ + h0 * DH + nt * 16 + fr] =
            f2bf(O[nt][i] * inv0[i]);
  }
  __syncthreads();   // all waves done reading P0

  // P1 -> LDS
  #pragma unroll
  for (int nt = 0; nt < 12; ++nt)
    #pragma unroll
    for (int i = 0; i < 4; ++i)
      Ps[(qbase - sq0 + i) * 200 + nt * 16 + fr] = f2bf(S1[nt][i]);
  __syncthreads();

  // PV head 1
  {
    f32x4 O[4];
    #pragma unroll
    for (int i = 0; i < 4; ++i) O[i] = (f32x4){0.f, 0.f, 0.f, 0.f};
    #pragma unroll
    for (int ks2 = 0; ks2 < 6; ++ks2) {
      const bf16x8 pa = *(const bf16x8*)&Ps[(qw + fr) * 200 + ks2 * 32 + fk];
      #pragma unroll
      for (int nt = 0; nt < 4; ++nt) {
        const bf16x8 vb = *(const bf16x8*)&Vt[(nt * 16 + fr) * 200 + ks2 * 32 + fk];
        O[nt] = __builtin_amdgcn_mfma_f32_16x16x32_bf16(pa, vb, O[nt], 0, 0, 0);
      }
    }
    #pragma unroll
    for (int nt = 0; nt < 4; ++nt)
      #pragma unroll
      for (int i = 0; i < 4; ++i)
        o[(size_t)(b * S_LEN + qbase + i) * QSZ + (h0 + 1) * DH + nt * 16 + fr] =
            f2bf(O[nt][i] * inv1[i]);
  }
}

extern "C" void kernel_launch(void* const* d_in, const int* in_sizes, int n_in,
                              void* d_out, int out_size, void* d_ws, size_t ws_size,
                              hipStream_t stream) {
  const float* hidden    = (const float*)d_in[0];
  const int*   positions = (const int*)d_in[1];
  const float* Wq = (const float*)d_in[2];
  const float* bq = (const float*)d_in[3];
  const float* Wk = (const float*)d_in[4];
  const float* bk = (const float*)d_in[5];
  const float* Wv = (const float*)d_in[6];
  const float* bv = (const float*)d_in[7];
  const float* Wo = (const float*)d_in[8];
  const float* bo = (const float*)d_in[9];
  float* out = (float*)d_out;

  // workspace:
  //   hbf   [2048][2880] bf16        @ 0          (11,796,480)
  //   WqkvT [5120][2880] bf16        @ 11796480   -- later WoT [2944][4096]
  //   q/o   [2048][4096] bf16        @ 41287680
  //   k     [2048][512]  bf16        @ 58064896
  //   vT    [512][2048]  bf16        @ 60162048
  char* ws = (char*)d_ws;
  unsigned short* hbf   = (unsigned short*)(ws);
  unsigned short* WqkvT = (unsigned short*)(ws + 11796480);
  unsigned short* qb    = (unsigned short*)(ws + 41287680);
  unsigned short* kb    = (unsigned short*)(ws + 58064896);
  unsigned short* vTb   = (unsigned short*)(ws + 60162048);

  const dim3 blk(256);
  convert_hidden<<<dim3((T_TOK * HIDN) / 2048), blk, 0, stream>>>(hidden, hbf);
  transpose_w<<<dim3(QSZ / 64, HIDN / 32), blk, 0, stream>>>(
      Wq, WqkvT, HIDN, QSZ);
  transpose_w<<<dim3(KVSZ / 64, HIDN / 32), blk, 0, stream>>>(
      Wk, WqkvT + (size_t)QSZ * HIDN, HIDN, KVSZ);
  transpose_w<<<dim3(KVSZ / 64, HIDN / 32), blk, 0, stream>>>(
      Wv, WqkvT + (size_t)(QSZ + KVSZ) * HIDN, HIDN, KVSZ);

  gemm_qkv<<<dim3(NQKV / 128, T_TOK / 128), blk, 0, stream>>>(
      hbf, WqkvT, bq, bk, bv, positions, qb, kb, vTb);

  // WoT (2944 padded rows) overwrites WqkvT after QKV GEMM consumed it
  transpose_w<<<dim3(NOPAD / 64, QSZ / 32), blk, 0, stream>>>(
      Wo, WqkvT, QSZ, HIDN);

  attn_kernel<<<dim3(S_LEN / 64, NHQ / 2, 2), blk, 0, stream>>>(
      qb, kb, vTb, qb);
  gemm_o<<<dim3(NOPAD / 128, T_TOK / 64), dim3(128), 0, stream>>>(
      qb, WqkvT, bo, out);
}

// Round 5
// 385.393 us; speedup vs baseline: 4.3701x; 1.0287x over previous
//
#include <hip/hip_runtime.h>

#define T_TOK 2048
#define S_LEN 1024
#define HIDN  2880
#define NHQ   64
#define NHKV  8
#define DH    64
#define QSZ   4096
#define KVSZ  512
#define WIN   128
#define NQKV  5120
#define NOPAD 2944

typedef __attribute__((ext_vector_type(4))) float f32x4;
typedef __attribute__((ext_vector_type(8))) short bf16x8;
typedef __attribute__((ext_vector_type(4))) short s16x4;

__device__ __forceinline__ unsigned short f2bf(float f) {
  unsigned u = __float_as_uint(f);
  u += 0x7fffu + ((u >> 16) & 1u);
  return (unsigned short)(u >> 16);
}
__device__ __forceinline__ float bf2f(unsigned short s) {
  return __uint_as_float(((unsigned)s) << 16);
}
__device__ __forceinline__ void ld_g2l16(const void* g, void* l) {
  __builtin_amdgcn_global_load_lds(
      (const __attribute__((address_space(1))) unsigned int*)g,
      (__attribute__((address_space(3))) unsigned int*)l, 16, 0, 0);
}

// ---------- merged prep: hidden fp32->bf16 + Wq/Wk/Wv transpose ----------
// flat grid: [0,2880) convert; [2880,8640) Wq; [8640,9360) Wk; [9360,10080) Wv
#define NB_CONV 2880
#define NB_WQ   5760
#define NB_WK   720

__device__ __forceinline__ void transpose_tile(
    const float* __restrict__ W, unsigned short* __restrict__ WT,
    int N, int lbid, float (*tile)[72])
{
  const int tid = threadIdx.x;
  const int nbx = N >> 6;
  const int nb = (lbid % nbx) * 64;
  const int kb = (lbid / nbx) * 32;
  const int kk = tid >> 3;
  const int n8 = (tid & 7) * 8;
  const float* src = W + (size_t)(kb + kk) * N + nb + n8;
  *(f32x4*)&tile[kk][n8]     = *(const f32x4*)(src);
  *(f32x4*)&tile[kk][n8 + 4] = *(const f32x4*)(src + 4);
  __syncthreads();
  const int n  = tid & 63;
  const int k8 = (tid >> 6) * 8;
  bf16x8 p;
  #pragma unroll
  for (int j = 0; j < 8; ++j) p[j] = (short)f2bf(tile[k8 + j][n]);
  *(bf16x8*)(WT + (size_t)(nb + n) * HIDN + kb + k8) = p;
}

__global__ __launch_bounds__(256) void prep_kernel(
    const float* __restrict__ hidden, unsigned short* __restrict__ hbf,
    const float* __restrict__ Wq, const float* __restrict__ Wk,
    const float* __restrict__ Wv, unsigned short* __restrict__ WT)
{
  __shared__ float tile[32][72];
  const int bid = blockIdx.x;
  if (bid < NB_CONV) {
    const size_t off = ((size_t)bid * 256 + threadIdx.x) * 8;
    const f32x4 a = *(const f32x4*)(hidden + off);
    const f32x4 b = *(const f32x4*)(hidden + off + 4);
    bf16x8 p;
    p[0] = (short)f2bf(a[0]); p[1] = (short)f2bf(a[1]);
    p[2] = (short)f2bf(a[2]); p[3] = (short)f2bf(a[3]);
    p[4] = (short)f2bf(b[0]); p[5] = (short)f2bf(b[1]);
    p[6] = (short)f2bf(b[2]); p[7] = (short)f2bf(b[3]);
    *(bf16x8*)(hbf + off) = p;
  } else if (bid < NB_CONV + NB_WQ) {
    transpose_tile(Wq, WT, QSZ, bid - NB_CONV, tile);
  } else if (bid < NB_CONV + NB_WQ + NB_WK) {
    transpose_tile(Wk, WT + (size_t)QSZ * HIDN, KVSZ,
                   bid - NB_CONV - NB_WQ, tile);
  } else {
    transpose_tile(Wv, WT + (size_t)(QSZ + KVSZ) * HIDN, KVSZ,
                   bid - NB_CONV - NB_WQ - NB_WK, tile);
  }
}

// ---- Wo [K=4096][N=2880] fp32 -> WT [2944 pad][4096] bf16 (edge-guarded) -
__global__ __launch_bounds__(256) void transpose_w(
    const float* __restrict__ W, unsigned short* __restrict__ WT,
    int K, int N)
{
  __shared__ float tile[32][72];
  const int tid = threadIdx.x;
  const int nb = blockIdx.x * 64;
  const int kb = blockIdx.y * 32;
  const int kk = tid >> 3;
  const int n8 = (tid & 7) * 8;
  if (nb + 64 <= N) {
    const float* src = W + (size_t)(kb + kk) * N + nb + n8;
    *(f32x4*)&tile[kk][n8]     = *(const f32x4*)(src);
    *(f32x4*)&tile[kk][n8 + 4] = *(const f32x4*)(src + 4);
  } else {
    #pragma unroll
    for (int u = 0; u < 8; ++u)
      tile[kk][n8 + u] = (nb + n8 + u < N)
          ? W[(size_t)(kb + kk) * N + nb + n8 + u] : 0.f;
  }
  __syncthreads();
  const int n  = tid & 63;
  const int k8 = (tid >> 6) * 8;
  bf16x8 p;
  #pragma unroll
  for (int j = 0; j < 8; ++j) p[j] = (short)f2bf(tile[k8 + j][n]);
  *(bf16x8*)(WT + (size_t)(nb + n) * K + kb + k8) = p;
}

// rope+bias epilogue for a 64-col group. C/D: col=lane&15, row=(lane>>4)*4+i.
__device__ __forceinline__ void rope_epilogue(
    f32x4 acc[4][4], const float* __restrict__ bias,
    const int* __restrict__ pos, unsigned short* __restrict__ outp,
    int outStride, int colbase, int rowbase, int lane)
{
  const int fr = lane & 15;
  const int r4 = (lane >> 4) * 4;
  const float invf0 = exp2f((float)fr        * (-17.19460283f / 32.0f));
  const float invf1 = exp2f((float)(fr + 16) * (-17.19460283f / 32.0f));
  #pragma unroll
  for (int mt = 0; mt < 4; ++mt) {
    #pragma unroll
    for (int i = 0; i < 4; ++i) {
      const int m = rowbase + mt * 16 + r4 + i;
      const float p = (float)pos[m];
      #pragma unroll
      for (int ntp = 0; ntp < 2; ++ntp) {
        float sv, cv;
        __sincosf(p * (ntp ? invf1 : invf0), &sv, &cv);
        const int c1 = colbase + ntp * 16 + fr;
        const float x1 = acc[mt][ntp][i]     + bias[c1];
        const float x2 = acc[mt][ntp + 2][i] + bias[c1 + 32];
        outp[(size_t)m * outStride + c1]      = f2bf(x1 * cv - x2 * sv);
        outp[(size_t)m * outStride + c1 + 32] = f2bf(x1 * sv + x2 * cv);
      }
    }
  }
}

// ---- fused QKV GEMM: 64m x 128n tile, 2 waves, BK=64, xor-swizzled LDS ---
__global__ __launch_bounds__(128) void gemm_qkv(
    const unsigned short* __restrict__ A, const unsigned short* __restrict__ BT,
    const float* __restrict__ bq, const float* __restrict__ bk,
    const float* __restrict__ bv, const int* __restrict__ pos,
    unsigned short* __restrict__ qb, unsigned short* __restrict__ kb,
    unsigned short* __restrict__ vT)
{
  __shared__ unsigned short As[64 * 64];
  __shared__ unsigned short Bs[128 * 64];
  const int tid  = threadIdx.x;
  const int lane = tid & 63;
  const int wid  = tid >> 6;             // 0..1
  const int m0 = blockIdx.y * 64;
  const int n0 = blockIdx.x * 128;
  const int wn = wid * 64;
  const int fr = lane & 15;
  const int fq = lane >> 4;

  f32x4 acc[4][4];
  #pragma unroll
  for (int i = 0; i < 4; ++i)
    #pragma unroll
    for (int j = 0; j < 4; ++j) acc[i][j] = (f32x4){0.f, 0.f, 0.f, 0.f};

  const int rsub = tid >> 3;             // 0..15
  const int cg   = (tid & 7) ^ (rsub & 7);
  const unsigned short* Ap = A  + (size_t)(m0 + rsub) * HIDN + cg * 8;
  const unsigned short* Bp = BT + (size_t)(n0 + rsub) * HIDN + cg * 8;
  const size_t rstep = (size_t)16 * HIDN;

  for (int k0 = 0; k0 < HIDN; k0 += 64) {
    #pragma unroll
    for (int i = 0; i < 4; ++i)
      ld_g2l16(Ap + i * rstep + k0, As + ((size_t)i * 128 + tid) * 8);
    #pragma unroll
    for (int i = 0; i < 8; ++i)
      ld_g2l16(Bp + i * rstep + k0, Bs + ((size_t)i * 128 + tid) * 8);
    __syncthreads();
    #pragma unroll
    for (int ks = 0; ks < 2; ++ks) {
      const int kc = ks * 4 + fq;
      bf16x8 af[4], bfr[4];
      #pragma unroll
      for (int mt = 0; mt < 4; ++mt) {
        const int R = mt * 16 + fr;
        af[mt] = *(const bf16x8*)(As + R * 64 + ((kc ^ (R & 7)) << 3));
      }
      #pragma unroll
      for (int nt = 0; nt < 4; ++nt) {
        const int R = wn + nt * 16 + fr;
        bfr[nt] = *(const bf16x8*)(Bs + R * 64 + ((kc ^ (R & 7)) << 3));
      }
      #pragma unroll
      for (int mt = 0; mt < 4; ++mt)
        #pragma unroll
        for (int nt = 0; nt < 4; ++nt)
          acc[mt][nt] = __builtin_amdgcn_mfma_f32_16x16x32_bf16(
              af[mt], bfr[nt], acc[mt][nt], 0, 0, 0);
    }
    __syncthreads();
  }

  const int r4 = (lane >> 4) * 4;
  if (n0 < QSZ) {
    rope_epilogue(acc, bq, pos, qb, QSZ, n0 + wn, m0, lane);
  } else if (n0 < QSZ + KVSZ) {
    rope_epilogue(acc, bk, pos, kb, KVSZ, n0 - QSZ + wn, m0, lane);
  } else {
    #pragma unroll
    for (int nt = 0; nt < 4; ++nt) {
      const int vrow = n0 - (QSZ + KVSZ) + wn + nt * 16 + fr;
      const float bvv = bv[vrow];
      #pragma unroll
      for (int mt = 0; mt < 4; ++mt) {
        const int mb = m0 + mt * 16 + r4;
        s16x4 p;
        p[0] = (short)f2bf(acc[mt][nt][0] + bvv);
        p[1] = (short)f2bf(acc[mt][nt][1] + bvv);
        p[2] = (short)f2bf(acc[mt][nt][2] + bvv);
        p[3] = (short)f2bf(acc[mt][nt][3] + bvv);
        *(s16x4*)(vT + (size_t)vrow * T_TOK + mb) = p;
      }
    }
  }
}

// ------- O-projection GEMM: 64m x 128n tile, 2 waves, BK=64, fp32 out -----
__global__ __launch_bounds__(128) void gemm_o(
    const unsigned short* __restrict__ A, const unsigned short* __restrict__ BT,
    const float* __restrict__ bias, float* __restrict__ C)
{
  __shared__ unsigned short As[64 * 64];
  __shared__ unsigned short Bs[128 * 64];
  const int tid  = threadIdx.x;
  const int lane = tid & 63;
  const int wid  = tid >> 6;
  const int m0 = blockIdx.y * 64;
  const int n0 = blockIdx.x * 128;
  const int wn = wid * 64;
  const int fr = lane & 15;
  const int fq = lane >> 4;

  f32x4 acc[4][4];
  #pragma unroll
  for (int i = 0; i < 4; ++i)
    #pragma unroll
    for (int j = 0; j < 4; ++j) acc[i][j] = (f32x4){0.f, 0.f, 0.f, 0.f};

  const int rsub = tid >> 3;
  const int cg   = (tid & 7) ^ (rsub & 7);
  const unsigned short* Ap = A  + (size_t)(m0 + rsub) * QSZ + cg * 8;
  const unsigned short* Bp = BT + (size_t)(n0 + rsub) * QSZ + cg * 8;
  const size_t rstep = (size_t)16 * QSZ;

  for (int k0 = 0; k0 < QSZ; k0 += 64) {
    #pragma unroll
    for (int i = 0; i < 4; ++i)
      ld_g2l16(Ap + i * rstep + k0, As + ((size_t)i * 128 + tid) * 8);
    #pragma unroll
    for (int i = 0; i < 8; ++i)
      ld_g2l16(Bp + i * rstep + k0, Bs + ((size_t)i * 128 + tid) * 8);
    __syncthreads();
    #pragma unroll
    for (int ks = 0; ks < 2; ++ks) {
      const int kc = ks * 4 + fq;
      bf16x8 af[4], bfr[4];
      #pragma unroll
      for (int mt = 0; mt < 4; ++mt) {
        const int R = mt * 16 + fr;
        af[mt] = *(const bf16x8*)(As + R * 64 + ((kc ^ (R & 7)) << 3));
      }
      #pragma unroll
      for (int nt = 0; nt < 4; ++nt) {
        const int R = wn + nt * 16 + fr;
        bfr[nt] = *(const bf16x8*)(Bs + R * 64 + ((kc ^ (R & 7)) << 3));
      }
      #pragma unroll
      for (int mt = 0; mt < 4; ++mt)
        #pragma unroll
        for (int nt = 0; nt < 4; ++nt)
          acc[mt][nt] = __builtin_amdgcn_mfma_f32_16x16x32_bf16(
              af[mt], bfr[nt], acc[mt][nt], 0, 0, 0);
    }
    __syncthreads();
  }

  const int r4 = (lane >> 4) * 4;
  #pragma unroll
  for (int nt = 0; nt < 4; ++nt) {
    const int n = n0 + wn + nt * 16 + fr;
    if (n >= HIDN) continue;
    const float bvv = bias[n];
    #pragma unroll
    for (int mt = 0; mt < 4; ++mt) {
      const int mb = m0 + mt * 16 + r4;
      #pragma unroll
      for (int i = 0; i < 4; ++i)
        C[(size_t)(mb + i) * HIDN + n] = acc[mt][nt][i] + bvv;
    }
  }
}

// ---------------- MFMA sliding-window GQA attention, 2 heads/block --------
__global__ __launch_bounds__(256, 3) void attn_kernel(
    const unsigned short* __restrict__ q, const unsigned short* __restrict__ k,
    const unsigned short* __restrict__ vT, unsigned short* __restrict__ o)
{
  __shared__ unsigned short lds[26624];     // 53,248 B -> 3 blocks/CU
  unsigned short* Ks = lds;                 // [192][72]
  unsigned short* Vt = lds;                 // [64][200] (over Ks)
  unsigned short* Ps = lds + 13824;         // [64][200]

  const int tid  = threadIdx.x;
  const int lane = tid & 63;
  const int wid  = tid >> 6;
  const int sq0  = blockIdx.x * 64;
  const int hp   = blockIdx.y;
  const int b    = blockIdx.z;
  const int h0   = hp * 2;
  const int kvh  = hp >> 2;
  const int kp0  = sq0 - WIN;

  const int fr = lane & 15;
  const int fk = (lane >> 4) * 8;
  const int qw = wid * 16;

  bf16x8 qf[2][2];
  {
    const size_t qrow = (size_t)(b * S_LEN + sq0 + qw + fr) * QSZ;
    #pragma unroll
    for (int hh = 0; hh < 2; ++hh)
      #pragma unroll
      for (int ks2 = 0; ks2 < 2; ++ks2)
        qf[hh][ks2] = *(const bf16x8*)(q + qrow + (h0 + hh) * DH + ks2 * 32 + fk);
  }

  #pragma unroll
  for (int j = 0; j < 6; ++j) {
    const int c  = tid + j * 256;
    const int kr = c >> 3, dc = (c & 7) * 8;
    int tok = b * S_LEN + kp0 + kr;
    if (tok < 0) tok = 0;                   // masked later
    const bf16x8 vv = *(const bf16x8*)(k + (size_t)tok * KVSZ + kvh * DH + dc);
    *(bf16x8*)&Ks[kr * 72 + dc] = vv;
  }
  __syncthreads();

  f32x4 S0[12], S1[12];
  #pragma unroll
  for (int i = 0; i < 12; ++i) {
    S0[i] = (f32x4){0.f, 0.f, 0.f, 0.f};
    S1[i] = (f32x4){0.f, 0.f, 0.f, 0.f};
  }
  #pragma unroll
  for (int ks2 = 0; ks2 < 2; ++ks2) {
    #pragma unroll
    for (int nt = 0; nt < 12; ++nt) {
      const bf16x8 bfr = *(const bf16x8*)&Ks[(nt * 16 + fr) * 72 + ks2 * 32 + fk];
      S0[nt] = __builtin_amdgcn_mfma_f32_16x16x32_bf16(qf[0][ks2], bfr, S0[nt], 0, 0, 0);
      S1[nt] = __builtin_amdgcn_mfma_f32_16x16x32_bf16(qf[1][ks2], bfr, S1[nt], 0, 0, 0);
    }
  }

  const int qbase = sq0 + qw + ((lane >> 4) << 2);
  float ls0[4] = {0.f, 0.f, 0.f, 0.f};
  float ls1[4] = {0.f, 0.f, 0.f, 0.f};
  #pragma unroll
  for (int nt = 0; nt < 12; ++nt) {
    const int jpos = kp0 + nt * 16 + fr;
    #pragma unroll
    for (int i = 0; i < 4; ++i) {
      const int qa = qbase + i;
      const bool valid = (jpos >= 0) && (jpos <= qa) && (jpos >= qa - WIN);
      const float e0 = valid ? __expf(S0[nt][i] * 0.125f) : 0.f;
      const float e1 = valid ? __expf(S1[nt][i] * 0.125f) : 0.f;
      S0[nt][i] = e0; ls0[i] += e0;
      S1[nt][i] = e1; ls1[i] += e1;
    }
  }
  #pragma unroll
  for (int off = 1; off < 16; off <<= 1)
    #pragma unroll
    for (int i = 0; i < 4; ++i) {
      ls0[i] += __shfl_xor(ls0[i], off, 64);
      ls1[i] += __shfl_xor(ls1[i], off, 64);
    }
  float inv0[4], inv1[4];
  #pragma unroll
  for (int i = 0; i < 4; ++i) {
    inv0[i] = 1.0f / ls0[i];
    inv1[i] = 1.0f / ls1[i];
  }
  __syncthreads();   // all waves done reading Ks

  #pragma unroll
  for (int nt = 0; nt < 12; ++nt)
    #pragma unroll
    for (int i = 0; i < 4; ++i)
      Ps[(qbase - sq0 + i) * 200 + nt * 16 + fr] = f2bf(S0[nt][i]);
  if (kp0 >= 0) {
    #pragma unroll
    for (int j = 0; j < 6; ++j) {
      const int c  = tid + j * 256;
      const int dr = c / 24, kc = (c % 24) * 8;
      const bf16x8 vv = *(const bf16x8*)(
          vT + (size_t)(kvh * DH + dr) * T_TOK + b * S_LEN + kp0 + kc);
      *(bf16x8*)&Vt[dr * 200 + kc] = vv;
    }
  } else {
    #pragma unroll
    for (int j = 0; j < 6; ++j) {
      const int c  = tid + j * 256;
      const int dr = c / 24, kc = (c % 24) * 8;
      bf16x8 vv;
      #pragma unroll
      for (int u = 0; u < 8; ++u) {
        int col = b * S_LEN + kp0 + kc + u;
        if (col < 0) col = 0;               // p==0 there
        vv[u] = (short)vT[(size_t)(kvh * DH + dr) * T_TOK + col];
      }
      *(bf16x8*)&Vt[dr * 200 + kc] = vv;
    }
  }
  __syncthreads();

  {
    f32x4 O[4];
    #pragma unroll
    for (int i = 0; i < 4; ++i) O[i] = (f32x4){0.f, 0.f, 0.f, 0.f};
    #pragma unroll
    for (int ks2 = 0; ks2 < 6; ++ks2) {
      const bf16x8 pa = *(const bf16x8*)&Ps[(qw + fr) * 200 + ks2 * 32 + fk];
      #pragma unroll
      for (int nt = 0; nt < 4; ++nt) {
        const bf16x8 vb = *(const bf16x8*)&Vt[(nt * 16 + fr) * 200 + ks2 * 32 + fk];
        O[nt] = __builtin_amdgcn_mfma_f32_16x16x32_bf16(pa, vb, O[nt], 0, 0, 0);
      }
    }
    #pragma unroll
    for (int nt = 0; nt < 4; ++nt)
      #pragma unroll
      for (int i = 0; i < 4; ++i)
        o[(size_t)(b * S_LEN + qbase + i) * QSZ + h0 * DH + nt * 16 + fr] =
            f2bf(O[nt][i] * inv0[i]);
  }
  __syncthreads();   // all waves done reading P0

  #pragma unroll
  for (int nt = 0; nt < 12; ++nt)
    #pragma unroll
    for (int i = 0; i < 4; ++i)
      Ps[(qbase - sq0 + i) * 200 + nt * 16 + fr] = f2bf(S1[nt][i]);
  __syncthreads();

  {
    f32x4 O[4];
    #pragma unroll
    for (int i = 0; i < 4; ++i) O[i] = (f32x4){0.f, 0.f, 0.f, 0.f};
    #pragma unroll
    for (int ks2 = 0; ks2 < 6; ++ks2) {
      const bf16x8 pa = *(const bf16x8*)&Ps[(qw + fr) * 200 + ks2 * 32 + fk];
      #pragma unroll
      for (int nt = 0; nt < 4; ++nt) {
        const bf16x8 vb = *(const bf16x8*)&Vt[(nt * 16 + fr) * 200 + ks2 * 32 + fk];
        O[nt] = __builtin_amdgcn_mfma_f32_16x16x32_bf16(pa, vb, O[nt], 0, 0, 0);
      }
    }
    #pragma unroll
    for (int nt = 0; nt < 4; ++nt)
      #pragma unroll
      for (int i = 0; i < 4; ++i)
        o[(size_t)(b * S_LEN + qbase + i) * QSZ + (h0 + 1) * DH + nt * 16 + fr] =
            f2bf(O[nt][i] * inv1[i]);
  }
}

extern "C" void kernel_launch(void* const* d_in, const int* in_sizes, int n_in,
                              void* d_out, int out_size, void* d_ws, size_t ws_size,
                              hipStream_t stream) {
  const float* hidden    = (const float*)d_in[0];
  const int*   positions = (const int*)d_in[1];
  const float* Wq = (const float*)d_in[2];
  const float* bq = (const float*)d_in[3];
  const float* Wk = (const float*)d_in[4];
  const float* bk = (const float*)d_in[5];
  const float* Wv = (const float*)d_in[6];
  const float* bv = (const float*)d_in[7];
  const float* Wo = (const float*)d_in[8];
  const float* bo = (const float*)d_in[9];
  float* out = (float*)d_out;

  // workspace:
  //   hbf   [2048][2880] bf16        @ 0          (11,796,480)
  //   WqkvT [5120][2880] bf16        @ 11796480   -- later WoT [2944][4096]
  //   q/o   [2048][4096] bf16        @ 41287680
  //   k     [2048][512]  bf16        @ 58064896
  //   vT    [512][2048]  bf16        @ 60162048
  char* ws = (char*)d_ws;
  unsigned short* hbf   = (unsigned short*)(ws);
  unsigned short* WqkvT = (unsigned short*)(ws + 11796480);
  unsigned short* qb    = (unsigned short*)(ws + 41287680);
  unsigned short* kb    = (unsigned short*)(ws + 58064896);
  unsigned short* vTb   = (unsigned short*)(ws + 60162048);

  prep_kernel<<<dim3(NB_CONV + NB_WQ + 2 * NB_WK), dim3(256), 0, stream>>>(
      hidden, hbf, Wq, Wk, Wv, WqkvT);

  gemm_qkv<<<dim3(NQKV / 128, T_TOK / 64), dim3(128), 0, stream>>>(
      hbf, WqkvT, bq, bk, bv, positions, qb, kb, vTb);

  // WoT (2944 padded rows) overwrites WqkvT after QKV GEMM consumed it
  transpose_w<<<dim3(NOPAD / 64, QSZ / 32), dim3(256), 0, stream>>>(
      Wo, WqkvT, QSZ, HIDN);

  attn_kernel<<<dim3(S_LEN / 64, NHQ / 2, 2), dim3(256), 0, stream>>>(
      qb, kb, vTb, qb);
  gemm_o<<<dim3(NOPAD / 128, T_TOK / 64), dim3(128), 0, stream>>>(
      qb, WqkvT, bo, out);
}